// Round 13
// baseline (131.443 us; speedup 1.0000x reference)
//
#include <hip/hip_runtime.h>
#include <hip/hip_bf16.h>
#include <math.h>

#define LN_EPS 1e-5f

typedef __attribute__((ext_vector_type(8))) short short8;
typedef __attribute__((ext_vector_type(4))) float f32x4;
typedef unsigned short u16;
typedef unsigned int u32;

__device__ __forceinline__ u16 f2bf(float f) {
  __hip_bfloat16 h = __float2bfloat16(f);
  return __builtin_bit_cast(u16, h);
}
__device__ __forceinline__ float bf2f(u16 u) {
  u32 x = ((u32)u) << 16;
  return __builtin_bit_cast(float, x);
}

// ---------------- wave reduction helpers ----------------
__device__ __forceinline__ float wave_sum64(float v) {
#pragma unroll
  for (int m = 1; m <= 32; m <<= 1) v += __shfl_xor(v, m, 64);
  return v;
}
__device__ __forceinline__ float grp32_sum(float v) {
#pragma unroll
  for (int m = 1; m <= 16; m <<= 1) v += __shfl_xor(v, m, 64);
  return v;
}

// ---------------- extractor body, R13: LDS-staged Wext + 2 rows/wave ----------------
// All weights bf16 in LDS (sWe bank-map (i*32+lane/2)%32 -> 2-way = free).
// Two rows processed simultaneously per wave: every weight read amortized
// over 2 rows, all latency chains doubled in ILP. Per-wave buffers -> no
// __syncthreads after the initial staging barrier (in-wave DS order, the
// mechanism proven by attn's lds_p reuse in R9-R12); fences pin compiler.
template <int DM>
__device__ __forceinline__ void extract_body(
    int rbase, u16* sWe, u16* sWq, u16* sWk, u16* sWv, float (*ybuf)[2][256],
    float (*fbuf)[2][64], const float* __restrict__ xin,
    const float* __restrict__ lng, const float* __restrict__ lnb,
    const float* __restrict__ Wext, const float* __restrict__ bext,
    const float* __restrict__ Wq, const float* __restrict__ bq,
    const float* __restrict__ Wk, const float* __restrict__ bk,
    const float* __restrict__ Wv, const float* __restrict__ bv,
    float* __restrict__ featOut, u16* __restrict__ Qout,
    u16* __restrict__ Kout, u16* __restrict__ Vout) {
  const int t = threadIdx.x, w = t >> 6, lane = t & 63;
  for (int i = t; i < DM * 64; i += 256) sWe[i] = f2bf(Wext[i]);
  for (int i = t; i < 4096; i += 256) {
    sWq[i] = f2bf(Wq[i]);
    sWk[i] = f2bf(Wk[i]);
    sWv[i] = f2bf(Wv[i]);
  }
  __syncthreads();

#pragma unroll
  for (int pp = 0; pp < 4; ++pp) {  // 4 passes x 2 rows = 8 rows/wave
    const int rA = rbase + w * 8 + pp * 2;
    const int rB = rA + 1;
    const float* xA = xin + (size_t)rA * DM;
    const float* xB = xin + (size_t)rB * DM;

    // ---- LayerNorm for both rows (interleaved chains) ----
    float xrA[4], xrB[4];
    float sA = 0.f, ssA = 0.f, sB = 0.f, ssB = 0.f;
#pragma unroll
    for (int u = 0; u < 4; ++u) {
      const int idx = u * 64 + lane;
      const float vA = (idx < DM) ? xA[idx] : 0.f;
      const float vB = (idx < DM) ? xB[idx] : 0.f;
      xrA[u] = vA;
      xrB[u] = vB;
      sA += vA;
      ssA += vA * vA;
      sB += vB;
      ssB += vB * vB;
    }
    sA = wave_sum64(sA);
    ssA = wave_sum64(ssA);
    sB = wave_sum64(sB);
    ssB = wave_sum64(ssB);
    const float mA = sA / (float)DM;
    const float rA_ = rsqrtf(ssA / (float)DM - mA * mA + LN_EPS);
    const float mB = sB / (float)DM;
    const float rB_ = rsqrtf(ssB / (float)DM - mB * mB + LN_EPS);
#pragma unroll
    for (int u = 0; u < 4; ++u) {
      const int idx = u * 64 + lane;
      if (idx < DM) {
        const float gg = lng[idx], bb = lnb[idx];
        ybuf[w][0][idx] = (xrA[u] - mA) * rA_ * gg + bb;
        ybuf[w][1][idx] = (xrB[u] - mB) * rB_ * gg + bb;
      }
    }
    asm volatile("" ::: "memory");  // in-wave DS order: writes before reads

    // ---- Linear(DM,64): weight read once, FMA into both rows ----
    float aA0 = bext[lane], aA1 = 0.f, aA2 = 0.f, aA3 = 0.f;
    float aB0 = aA0, aB1 = 0.f, aB2 = 0.f, aB3 = 0.f;
    int i = 0;
#pragma unroll 2
    for (; i + 4 <= DM; i += 4) {
      const float w0 = bf2f(sWe[(i + 0) * 64 + lane]);
      const float w1 = bf2f(sWe[(i + 1) * 64 + lane]);
      const float w2 = bf2f(sWe[(i + 2) * 64 + lane]);
      const float w3 = bf2f(sWe[(i + 3) * 64 + lane]);
      aA0 = fmaf(ybuf[w][0][i + 0], w0, aA0);
      aA1 = fmaf(ybuf[w][0][i + 1], w1, aA1);
      aA2 = fmaf(ybuf[w][0][i + 2], w2, aA2);
      aA3 = fmaf(ybuf[w][0][i + 3], w3, aA3);
      aB0 = fmaf(ybuf[w][1][i + 0], w0, aB0);
      aB1 = fmaf(ybuf[w][1][i + 1], w1, aB1);
      aB2 = fmaf(ybuf[w][1][i + 2], w2, aB2);
      aB3 = fmaf(ybuf[w][1][i + 3], w3, aB3);
    }
    for (; i < DM; ++i) {
      const float wv = bf2f(sWe[i * 64 + lane]);
      aA0 = fmaf(ybuf[w][0][i], wv, aA0);
      aB0 = fmaf(ybuf[w][1][i], wv, aB0);
    }
    const float fA = fmaxf((aA0 + aA1) + (aA2 + aA3), 0.f);
    const float fB = fmaxf((aB0 + aB1) + (aB2 + aB3), 0.f);
    featOut[(size_t)rA * 64 + lane] = fA;
    featOut[(size_t)rB * 64 + lane] = fB;
    fbuf[w][0][lane] = fA;
    fbuf[w][1][lane] = fB;
    asm volatile("" ::: "memory");  // writes before reads

    // ---- QKV projections: weights read once, both rows ----
    float aqA = bq[lane], akA = bk[lane], avA = bv[lane];
    float aqB = aqA, akB = akA, avB = avA;
#pragma unroll 8
    for (int j = 0; j < 64; ++j) {
      const float wq = bf2f(sWq[j * 64 + lane]);
      const float wk = bf2f(sWk[j * 64 + lane]);
      const float wv = bf2f(sWv[j * 64 + lane]);
      const float fvA = fbuf[w][0][j], fvB = fbuf[w][1][j];
      aqA = fmaf(fvA, wq, aqA);
      akA = fmaf(fvA, wk, akA);
      avA = fmaf(fvA, wv, avA);
      aqB = fmaf(fvB, wq, aqB);
      akB = fmaf(fvB, wk, akB);
      avB = fmaf(fvB, wv, avB);
    }
    Qout[(size_t)rA * 64 + lane] = f2bf(aqA * 0.125f);  // fold 1/sqrt(64)
    Kout[(size_t)rA * 64 + lane] = f2bf(akA);
    Vout[(size_t)rA * 64 + lane] = f2bf(avA);
    Qout[(size_t)rB * 64 + lane] = f2bf(aqB * 0.125f);
    Kout[(size_t)rB * 64 + lane] = f2bf(akB);
    Vout[(size_t)rB * 64 + lane] = f2bf(avB);
    asm volatile("" ::: "memory");  // reads before next pass's overwrite
  }
}

// ---------------- fused extractor: blocks [0,256) nir, [256,512) libs ----------------
__global__ __launch_bounds__(256) void extract_fused_kernel(
    const float* __restrict__ nir_x, const float* __restrict__ libs_x,
    const float* __restrict__ n_lng, const float* __restrict__ n_lnb,
    const float* __restrict__ n_We, const float* __restrict__ n_be,
    const float* __restrict__ l_lng, const float* __restrict__ l_lnb,
    const float* __restrict__ l_We, const float* __restrict__ l_be,
    const float* __restrict__ q_ln_w, const float* __restrict__ q_ln_b,
    const float* __restrict__ k_ln_w, const float* __restrict__ k_ln_b,
    const float* __restrict__ v_ln_w, const float* __restrict__ v_ln_b,
    const float* __restrict__ q_nl_w, const float* __restrict__ q_nl_b,
    const float* __restrict__ k_nl_w, const float* __restrict__ k_nl_b,
    const float* __restrict__ v_nl_w, const float* __restrict__ v_nl_b,
    float* __restrict__ f_nir, float* __restrict__ f_libs,
    u16* __restrict__ Qb_nir, u16* __restrict__ Kb_nir,
    u16* __restrict__ Vb_nir, u16* __restrict__ Qb_libs,
    u16* __restrict__ Kb_libs, u16* __restrict__ Vb_libs) {
  __shared__ u16 sWe[244 * 64];
  __shared__ u16 sWq[4096], sWk[4096], sWv[4096];
  __shared__ float ybuf[4][2][256];
  __shared__ float fbuf[4][2][64];
  if (blockIdx.x < 256) {
    // nir: Q uses q_nl, K/V use *_ln
    extract_body<215>(blockIdx.x * 32, sWe, sWq, sWk, sWv, ybuf, fbuf, nir_x,
                      n_lng, n_lnb, n_We, n_be, q_nl_w, q_nl_b, k_ln_w,
                      k_ln_b, v_ln_w, v_ln_b, f_nir, Qb_nir, Kb_nir, Vb_nir);
  } else {
    // libs: Q uses q_ln, K/V use *_nl
    extract_body<244>((blockIdx.x - 256) * 32, sWe, sWq, sWk, sWv, ybuf, fbuf,
                      libs_x, l_lng, l_lnb, l_We, l_be, q_ln_w, q_ln_b,
                      k_nl_w, k_nl_b, v_nl_w, v_nl_b, f_libs, Qb_libs,
                      Kb_libs, Vb_libs);
  }
}

// ---------------- flash attention (R12-proven, byte-identical) ----------------
__global__ __launch_bounds__(256, 2) void attn_mfma_kernel(
    const u16* __restrict__ Qb0, const u16* __restrict__ Kb0,
    const u16* __restrict__ Vb0, const u16* __restrict__ Qb1,
    const u16* __restrict__ Kb1, const u16* __restrict__ Vb1,
    u16* __restrict__ Opart, float* __restrict__ lpart) {
  __shared__ __align__(16) u16 lds_k[4096];    // [kv][d] ^ ((kv&7)<<3)
  __shared__ __align__(16) u16 lds_vt[4096];   // [d][kv] ^ (((d>>1)&7)<<3)
  __shared__ __align__(16) u32 lds_p[4][544];  // per-wave [16 q][34], reused per sub

  const int bid = blockIdx.x;
  const int split = bid & 7;
  const int dir = (bid >> 3) & 1;
  const int qt = bid >> 4;
  const int slab = dir * 8 + split;
  const int kvbase = split * 1024;

  const u16* Q = dir ? Qb1 : Qb0;
  const u16* K = dir ? Kb1 : Kb0;
  const u16* V = dir ? Vb1 : Vb0;

  const int t = threadIdx.x;
  const int w = t >> 6;
  const int lane = t & 63;
  const int g = lane >> 4;
  const int l16 = lane & 15;
  const int qblk = qt * 256 + w * 64;

  // ---- Q B-fragments: 4 q-subtiles x 2 k-chunks (pre-scaled by 1/8) ----
  short8 qa[4][2];
#pragma unroll
  for (int sub = 0; sub < 4; ++sub)
#pragma unroll
    for (int c = 0; c < 2; ++c)
      qa[sub][c] = *reinterpret_cast<const short8*>(
          Q + (size_t)(qblk + sub * 16 + l16) * 64 + 32 * c + 8 * g);

  f32x4 oacc[4][4];
#pragma unroll
  for (int sub = 0; sub < 4; ++sub)
#pragma unroll
    for (int db = 0; db < 4; ++db) oacc[sub][db] = f32x4{0.f, 0.f, 0.f, 0.f};
  float l_run[4] = {0.f, 0.f, 0.f, 0.f};

  const int kv0 = (t >> 4) << 2;
  const int d0 = (t & 15) << 2;
  ushort4 kh[4], vh[4];

#define LOADT(tile_)                                                          \
  {                                                                           \
    _Pragma("unroll") for (int j = 0; j < 4; ++j) {                           \
      const size_t off = ((size_t)(kvbase + (tile_)*64 + kv0 + j)) * 64 + d0; \
      kh[j] = *reinterpret_cast<const ushort4*>(K + off);                     \
      vh[j] = *reinterpret_cast<const ushort4*>(V + off);                     \
    }                                                                         \
  }

#define STORET()                                                              \
  {                                                                           \
    _Pragma("unroll") for (int j = 0; j < 4; ++j) {                           \
      const int row = kv0 + j;                                                \
      *reinterpret_cast<ushort4*>(                                            \
          &lds_k[(row * 64 + d0) ^ ((row & 7) << 3)]) = kh[j];                \
    }                                                                         \
    _Pragma("unroll") for (int i = 0; i < 4; ++i) {                           \
      const int row = d0 + i;                                                 \
      ushort4 vt;                                                             \
      vt.x = (&vh[0].x)[i];                                                   \
      vt.y = (&vh[1].x)[i];                                                   \
      vt.z = (&vh[2].x)[i];                                                   \
      vt.w = (&vh[3].x)[i];                                                   \
      *reinterpret_cast<ushort4*>(                                            \
          &lds_vt[(row * 64 + kv0) ^ (((row >> 1) & 7) << 3)]) = vt;          \
    }                                                                         \
  }

  LOADT(0);
  STORET();
  LOADT(1);
  asm volatile("s_waitcnt lgkmcnt(0)" ::: "memory");
  __builtin_amdgcn_s_barrier();
  asm volatile("" ::: "memory");

  for (int tile = 0; tile < 16; ++tile) {
    // ---- S^T = K Q for all 4 subs (K-fragment loaded once) ----
    f32x4 sacc[4][4];
#pragma unroll
    for (int sub = 0; sub < 4; ++sub)
#pragma unroll
      for (int kb = 0; kb < 4; ++kb) sacc[sub][kb] = f32x4{0.f, 0.f, 0.f, 0.f};
#pragma unroll
    for (int c = 0; c < 2; ++c) {
#pragma unroll
      for (int kb = 0; kb < 4; ++kb) {
        const int row = 16 * kb + l16;
        const int idx = (row * 64 + 32 * c + 8 * g) ^ ((row & 7) << 3);
        const short8 kfrag = *reinterpret_cast<const short8*>(&lds_k[idx]);
#pragma unroll
        for (int sub = 0; sub < 4; ++sub)
          sacc[sub][kb] = __builtin_amdgcn_mfma_f32_16x16x32_bf16(
              kfrag, qa[sub][c], sacc[sub][kb], 0, 0, 0);
      }
    }

    // ---- no-max softmax (__expf); per-sub P round-trip via reused buffer ----
    short8 pB[4][2];
#pragma unroll
    for (int sub = 0; sub < 4; ++sub) {
      float lsub = 0.f;
#pragma unroll
      for (int kb = 0; kb < 4; ++kb) {
        const float p0 = __expf(sacc[sub][kb][0]);
        const float p1 = __expf(sacc[sub][kb][1]);
        const float p2 = __expf(sacc[sub][kb][2]);
        const float p3 = __expf(sacc[sub][kb][3]);
        lsub += (p0 + p1) + (p2 + p3);
        u32 w0, w1;
        asm("v_cvt_pk_bf16_f32 %0, %1, %2" : "=v"(w0) : "v"(p0), "v"(p1));
        asm("v_cvt_pk_bf16_f32 %0, %1, %2" : "=v"(w1) : "v"(p2), "v"(p3));
        *reinterpret_cast<uint2*>(&lds_p[w][l16 * 34 + 8 * kb + 2 * g]) =
            make_uint2(w0, w1);
      }
      l_run[sub] += lsub;
      asm volatile("" ::: "memory");  // writes before reads (in-wave DS order)
#pragma unroll
      for (int c = 0; c < 2; ++c) {
        const int base = l16 * 34 + 16 * c + 4 * g;
        const uint2 a = *reinterpret_cast<const uint2*>(&lds_p[w][base]);
        const uint2 bb = *reinterpret_cast<const uint2*>(&lds_p[w][base + 2]);
        u32 q4[4] = {a.x, a.y, bb.x, bb.y};
        pB[sub][c] = __builtin_bit_cast(short8, *(ulonglong2*)q4);
      }
      asm volatile("" ::: "memory");  // reads before next sub's overwrite
    }

    // ---- O^T += V^T P^T (V-fragment loaded once, shared by 4 subs) ----
#pragma unroll
    for (int c = 0; c < 2; ++c) {
#pragma unroll
      for (int db = 0; db < 4; ++db) {
        const int row = 16 * db + l16;
        const int idx = (row * 64 + 32 * c + 8 * g) ^ (((row >> 1) & 7) << 3);
        const short8 vfrag = *reinterpret_cast<const short8*>(&lds_vt[idx]);
#pragma unroll
        for (int sub = 0; sub < 4; ++sub)
          oacc[sub][db] = __builtin_amdgcn_mfma_f32_16x16x32_bf16(
              vfrag, pB[sub][c], oacc[sub][db], 0, 0, 0);
      }
    }

    // ---- rotate single K/V buffer ----
    asm volatile("s_waitcnt lgkmcnt(0)" ::: "memory");
    __builtin_amdgcn_s_barrier();
    asm volatile("" ::: "memory");
    if (tile < 15) {
      STORET();
      if (tile < 14) LOADT(tile + 2);
    }
    asm volatile("s_waitcnt lgkmcnt(0)" ::: "memory");
    __builtin_amdgcn_s_barrier();
    asm volatile("" ::: "memory");
  }

  // ---- epilogue: bf16 unnormalized O + f32 l ----
  const size_t S = (size_t)8192 * 64;
#pragma unroll
  for (int sub = 0; sub < 4; ++sub) {
    const int q = qblk + sub * 16 + l16;
#pragma unroll
    for (int db = 0; db < 4; ++db) {
      u32 w0, w1;
      asm("v_cvt_pk_bf16_f32 %0, %1, %2"
          : "=v"(w0)
          : "v"(oacc[sub][db][0]), "v"(oacc[sub][db][1]));
      asm("v_cvt_pk_bf16_f32 %0, %1, %2"
          : "=v"(w1)
          : "v"(oacc[sub][db][2]), "v"(oacc[sub][db][3]));
      *reinterpret_cast<uint2*>(Opart + (size_t)slab * S + (size_t)q * 64 +
                                16 * db + 4 * g) = make_uint2(w0, w1);
    }
    float lv = l_run[sub];
    lv += __shfl_xor(lv, 16, 64);
    lv += __shfl_xor(lv, 32, 64);
    if (g == 0) lpart[slab * 8192 + q] = lv;
  }
#undef LOADT
#undef STORET
}

// ---------------- post (R12-proven, byte-identical) ----------------
__global__ __launch_bounds__(256) void post_kernel(
    const u16* __restrict__ Opart, const float* __restrict__ lpart,
    const float* __restrict__ nirF, const float* __restrict__ libsF,
    const float* __restrict__ ln1g, const float* __restrict__ ln1b,
    const float* __restrict__ fc1w, const float* __restrict__ fc1b,
    const float* __restrict__ ln2g, const float* __restrict__ ln2b,
    const float* __restrict__ fc2w, const float* __restrict__ fc2b,
    const float* __restrict__ ln0g, const float* __restrict__ ln0b,
    const float* __restrict__ gatew, const float* __restrict__ gateb,
    const float* __restrict__ ln3g, const float* __restrict__ ln3b,
    const float* __restrict__ fc3w, const float* __restrict__ fc3b,
    const float* __restrict__ ln4g, const float* __restrict__ ln4b,
    const float* __restrict__ fc4w, const float* __restrict__ fc4b,
    float* __restrict__ out) {
  __shared__ u16 FC1[4096], FC2[4096], FC3[2048];
  __shared__ u16 GW[8192];
  __shared__ float rbuf[4][128];
  const int t = threadIdx.x, w = t >> 6, lane = t & 63;
  const size_t S = (size_t)8192 * 64;
  for (int i = t; i < 4096; i += 256) {
    FC1[i] = f2bf(fc1w[i]);
    FC2[i] = f2bf(fc2w[i]);
  }
  for (int i = t; i < 2048; i += 256) FC3[i] = f2bf(fc3w[i]);
  for (int i = t; i < 8192; i += 256) GW[i] = f2bf(gatew[i]);
  __syncthreads();
#pragma unroll
  for (int rr = 0; rr < 2; ++rr) {
    const int r = blockIdx.x * 8 + rr * 4 + w;
    const size_t ro = (size_t)r * 64;

    // merge 8 KV-splits per direction (no-max: plain sums), bf16 partials
    float a1 = 0.f, a2 = 0.f, l1 = 0.f, l2 = 0.f;
#pragma unroll
    for (int s = 0; s < 8; ++s) {
      a1 += bf2f(Opart[(size_t)s * S + ro + lane]);
      a2 += bf2f(Opart[(size_t)(8 + s) * S + ro + lane]);
      l1 += lpart[s * 8192 + r];
      l2 += lpart[(8 + s) * 8192 + r];
    }
    a1 /= l1;  // attn_libs_to_nir
    a2 /= l2;  // attn_nir_to_libs

    const float nv = nirF[ro + lane], lv_ = libsF[ro + lane];

    // out1 = relu(LN(a2; ln1) @ fc1 + b) + libs
    float s1 = wave_sum64(a2), ss1 = wave_sum64(a2 * a2);
    float mean = s1 * (1.f / 64);
    float rstd = rsqrtf(ss1 * (1.f / 64) - mean * mean + LN_EPS);
    rbuf[w][lane] = (a2 - mean) * rstd * ln1g[lane] + ln1b[lane];
    __syncthreads();
    float o1 = fc1b[lane];
#pragma unroll 8
    for (int i = 0; i < 64; ++i)
      o1 = fmaf(rbuf[w][i], bf2f(FC1[i * 64 + lane]), o1);
    const float out1 = fmaxf(o1, 0.f) + lv_;
    __syncthreads();

    // out2 = relu(LN(a1; ln2) @ fc2 + b) + nir
    s1 = wave_sum64(a1);
    ss1 = wave_sum64(a1 * a1);
    mean = s1 * (1.f / 64);
    rstd = rsqrtf(ss1 * (1.f / 64) - mean * mean + LN_EPS);
    rbuf[w][lane] = (a1 - mean) * rstd * ln2g[lane] + ln2b[lane];
    __syncthreads();
    float o2 = fc2b[lane];
#pragma unroll 8
    for (int i = 0; i < 64; ++i)
      o2 = fmaf(rbuf[w][i], bf2f(FC2[i * 64 + lane]), o2);
    const float out2 = fmaxf(o2, 0.f) + nv;
    __syncthreads();

    // gate
    s1 = wave_sum64(out1 + out2);
    ss1 = wave_sum64(out1 * out1 + out2 * out2);
    mean = s1 * (1.f / 128);
    rstd = rsqrtf(ss1 * (1.f / 128) - mean * mean + LN_EPS);
    rbuf[w][lane] = (out1 - mean) * rstd * ln0g[lane] + ln0b[lane];
    rbuf[w][64 + lane] =
        (out2 - mean) * rstd * ln0g[64 + lane] + ln0b[64 + lane];
    __syncthreads();
    float gg = gateb[lane];
#pragma unroll 8
    for (int i = 0; i < 128; ++i)
      gg = fmaf(rbuf[w][i], bf2f(GW[i * 64 + lane]), gg);
    gg = 1.f / (1.f + __expf(-gg));
    const float fused = gg * out1 + (1.f - gg) * out2;
    __syncthreads();

    // head: LN -> fc3 -> relu -> LN -> fc4
    s1 = wave_sum64(fused);
    ss1 = wave_sum64(fused * fused);
    mean = s1 * (1.f / 64);
    rstd = rsqrtf(ss1 * (1.f / 64) - mean * mean + LN_EPS);
    rbuf[w][lane] = (fused - mean) * rstd * ln3g[lane] + ln3b[lane];
    __syncthreads();
    if (lane < 32) {
      float h = fc3b[lane];
#pragma unroll 8
      for (int i = 0; i < 64; ++i)
        h = fmaf(rbuf[w][i], bf2f(FC3[i * 32 + lane]), h);
      h = fmaxf(h, 0.f);
      const float hs = grp32_sum(h), hss = grp32_sum(h * h);
      const float hm = hs * (1.f / 32);
      const float hr = rsqrtf(hss * (1.f / 32) - hm * hm + LN_EPS);
      const float y4 = (h - hm) * hr * ln4g[lane] + ln4b[lane];
      const float part = grp32_sum(y4 * fc4w[lane]);
      if (lane == 0) out[r] = part + fc4b[0];
    }
    __syncthreads();
  }
}

extern "C" void kernel_launch(void* const* d_in, const int* in_sizes, int n_in,
                              void* d_out, int out_size, void* d_ws,
                              size_t ws_size, hipStream_t stream) {
  const float* nir_data = (const float*)d_in[0];
  const float* libs_data = (const float*)d_in[1];
  const float* nir_ln_g = (const float*)d_in[2];
  const float* nir_ln_b = (const float*)d_in[3];
  const float* nir_w = (const float*)d_in[4];
  const float* nir_b = (const float*)d_in[5];
  const float* libs_ln_g = (const float*)d_in[6];
  const float* libs_ln_b = (const float*)d_in[7];
  const float* libs_w = (const float*)d_in[8];
  const float* libs_b = (const float*)d_in[9];
  const float* q_ln_w = (const float*)d_in[10];
  const float* q_ln_b = (const float*)d_in[11];
  const float* k_ln_w = (const float*)d_in[12];
  const float* k_ln_b = (const float*)d_in[13];
  const float* v_ln_w = (const float*)d_in[14];
  const float* v_ln_b = (const float*)d_in[15];
  const float* q_nl_w = (const float*)d_in[16];
  const float* q_nl_b = (const float*)d_in[17];
  const float* k_nl_w = (const float*)d_in[18];
  const float* k_nl_b = (const float*)d_in[19];
  const float* v_nl_w = (const float*)d_in[20];
  const float* v_nl_b = (const float*)d_in[21];
  const float* ln1_g = (const float*)d_in[22];
  const float* ln1_b = (const float*)d_in[23];
  const float* fc1_w = (const float*)d_in[24];
  const float* fc1_b = (const float*)d_in[25];
  const float* ln2_g = (const float*)d_in[26];
  const float* ln2_b = (const float*)d_in[27];
  const float* fc2_w = (const float*)d_in[28];
  const float* fc2_b = (const float*)d_in[29];
  const float* ln0_g = (const float*)d_in[30];
  const float* ln0_b = (const float*)d_in[31];
  const float* gate_w = (const float*)d_in[32];
  const float* gate_b = (const float*)d_in[33];
  const float* ln3_g = (const float*)d_in[34];
  const float* ln3_b = (const float*)d_in[35];
  const float* fc3_w = (const float*)d_in[36];
  const float* fc3_b = (const float*)d_in[37];
  const float* ln4_g = (const float*)d_in[38];
  const float* ln4_b = (const float*)d_in[39];
  const float* fc4_w = (const float*)d_in[40];
  const float* fc4_b = (const float*)d_in[41];

  const size_t S = (size_t)8192 * 64;
  u16* ub = (u16*)d_ws;
  u16* Qb_nir = ub + 0 * S;
  u16* Kb_nir = ub + 1 * S;
  u16* Vb_nir = ub + 2 * S;
  u16* Qb_libs = ub + 3 * S;
  u16* Kb_libs = ub + 4 * S;
  u16* Vb_libs = ub + 5 * S;
  u16* OpartU = ub + 6 * S;  // 16 slabs bf16 (2 dirs x 8 splits)
  float* fp = (float*)(ub + 22 * S);
  float* f_nir = fp + 0 * S;
  float* f_libs = fp + 1 * S;
  float* lpart = fp + 2 * S;  // 16 x 8192

  extract_fused_kernel<<<512, 256, 0, stream>>>(
      nir_data, libs_data, nir_ln_g, nir_ln_b, nir_w, nir_b, libs_ln_g,
      libs_ln_b, libs_w, libs_b, q_ln_w, q_ln_b, k_ln_w, k_ln_b, v_ln_w,
      v_ln_b, q_nl_w, q_nl_b, k_nl_w, k_nl_b, v_nl_w, v_nl_b, f_nir, f_libs,
      Qb_nir, Kb_nir, Vb_nir, Qb_libs, Kb_libs, Vb_libs);

  // dir0: Q_libs x K/V_nir ; dir1: Q_nir x K/V_libs
  attn_mfma_kernel<<<512, 256, 0, stream>>>(Qb_libs, Kb_nir, Vb_nir, Qb_nir,
                                            Kb_libs, Vb_libs, OpartU, lpart);

  post_kernel<<<1024, 256, 0, stream>>>(
      OpartU, lpart, f_nir, f_libs, ln1_g, ln1_b, fc1_w, fc1_b, ln2_g, ln2_b,
      fc2_w, fc2_b, ln0_g, ln0_b, gate_w, gate_b, ln3_g, ln3_b, fc3_w, fc3_b,
      ln4_g, ln4_b, fc4_w, fc4_b, (float*)d_out);
}

// Round 14
// 94.194 us; speedup vs baseline: 1.3954x; 1.3954x over previous
//
#include <hip/hip_runtime.h>
#include <hip/hip_bf16.h>
#include <math.h>

#define LN_EPS 1e-5f

typedef __attribute__((ext_vector_type(8))) short short8;
typedef __attribute__((ext_vector_type(4))) float f32x4;
typedef unsigned short u16;
typedef unsigned int u32;

__device__ __forceinline__ u16 f2bf(float f) {
  __hip_bfloat16 h = __float2bfloat16(f);
  return __builtin_bit_cast(u16, h);
}
__device__ __forceinline__ float bf2f(u16 u) {
  u32 x = ((u32)u) << 16;
  return __builtin_bit_cast(float, x);
}

// ---------------- wave reduction helpers ----------------
__device__ __forceinline__ float wave_sum64(float v) {
#pragma unroll
  for (int m = 1; m <= 32; m <<= 1) v += __shfl_xor(v, m, 64);
  return v;
}
__device__ __forceinline__ float grp32_sum(float v) {
#pragma unroll
  for (int m = 1; m <= 16; m <<= 1) v += __shfl_xor(v, m, 64);
  return v;
}

// ---------------- extractor, MFMA version (R14) ----------------
// Block = 32 rows, 4 waves. Wave w owns output-col slice [16w,16w+16).
// Fragment algebra mirrors the attention kernel's proven mfma(kfrag, qa):
//   out = mfma(A=W^T-frag, B=x-frag): lane l16 = x-row (B-row), (g,r_) =
//   output col within the wave's 16-col slice; identical C/D write pattern
//   to the attention epilogue. A-frags are gathered ONCE per block from the
//   original f32 weights into registers (no weight LDS, no per-row re-read).
// xt: LN'd rows bf16 [32][256] (K zero-padded), attention XOR swizzle
// ((row&7)<<3 on u16 index) -> b128 reads 2-way/free.
// ft: Feat bf16 [32][64], same swizzle.
template <int DM, int KSTEPS>
__device__ __forceinline__ void extract_mfma_body(
    int rbase, u16* xt, u16* ft, const float* __restrict__ xin,
    const float* __restrict__ lng, const float* __restrict__ lnb,
    const float* __restrict__ We, const float* __restrict__ be,
    const float* __restrict__ Wq, const float* __restrict__ bq,
    const float* __restrict__ Wk, const float* __restrict__ bk,
    const float* __restrict__ Wv, const float* __restrict__ bv,
    float* __restrict__ featOut, u16* __restrict__ Qout,
    u16* __restrict__ Kout, u16* __restrict__ Vout) {
  const int t = threadIdx.x, w = t >> 6, lane = t & 63;
  const int g = lane >> 4, l16 = lane & 15;
  const int c = 16 * w + l16;  // A-frag row = this lane's weight column

  // ---- A-fragments: gather f32 weights -> bf16 regs (issued early) ----
  short8 wf[KSTEPS];
#pragma unroll
  for (int kc = 0; kc < KSTEPS; ++kc) {
    short8 f;
#pragma unroll
    for (int i = 0; i < 8; ++i) {
      const int k = kc * 32 + 8 * g + i;
      f[i] = (short)((k < DM) ? f2bf(We[(size_t)k * 64 + c]) : (u16)0);
    }
    wf[kc] = f;
  }
  short8 qf[2], kf[2], vf[2];
#pragma unroll
  for (int kc = 0; kc < 2; ++kc) {
    short8 fq, fk, fv;
#pragma unroll
    for (int i = 0; i < 8; ++i) {
      const int k = kc * 32 + 8 * g + i;
      fq[i] = (short)f2bf(Wq[k * 64 + c]);
      fk[i] = (short)f2bf(Wk[k * 64 + c]);
      fv[i] = (short)f2bf(Wv[k * 64 + c]);
    }
    qf[kc] = fq;
    kf[kc] = fk;
    vf[kc] = fv;
  }

  // ---- LN: 8 rows/wave (4 passes x 2-row ILP), bf16 swizzled xt ----
#pragma unroll
  for (int pp = 0; pp < 4; ++pp) {
    const int lrA = 8 * w + pp * 2;
    const int lrB = lrA + 1;
    const float* xA = xin + (size_t)(rbase + lrA) * DM;
    const float* xB = xin + (size_t)(rbase + lrB) * DM;
    float xrA[4], xrB[4];
    float sA = 0.f, ssA = 0.f, sB = 0.f, ssB = 0.f;
#pragma unroll
    for (int u = 0; u < 4; ++u) {
      const int idx = u * 64 + lane;
      const float vA = (idx < DM) ? xA[idx] : 0.f;
      const float vB = (idx < DM) ? xB[idx] : 0.f;
      xrA[u] = vA;
      xrB[u] = vB;
      sA += vA;
      ssA += vA * vA;
      sB += vB;
      ssB += vB * vB;
    }
    sA = wave_sum64(sA);
    ssA = wave_sum64(ssA);
    sB = wave_sum64(sB);
    ssB = wave_sum64(ssB);
    const float mA = sA / (float)DM;
    const float rAs = rsqrtf(ssA / (float)DM - mA * mA + LN_EPS);
    const float mB = sB / (float)DM;
    const float rBs = rsqrtf(ssB / (float)DM - mB * mB + LN_EPS);
#pragma unroll
    for (int u = 0; u < 4; ++u) {
      const int idx = u * 64 + lane;
      float yA = 0.f, yB = 0.f;
      if (idx < DM) {
        const float gg = lng[idx], bb = lnb[idx];
        yA = (xrA[u] - mA) * rAs * gg + bb;
        yB = (xrB[u] - mB) * rBs * gg + bb;
      }
      xt[(lrA * 256 + idx) ^ ((lrA & 7) << 3)] = f2bf(yA);
      xt[(lrB * 256 + idx) ^ ((lrB & 7) << 3)] = f2bf(yB);
    }
  }
  __syncthreads();

  // ---- Feat = LN(x) @ We + be, ReLU -> f32 featOut + bf16 ft ----
  const float4 bev = *reinterpret_cast<const float4*>(&be[16 * w + 4 * g]);
#pragma unroll
  for (int sub = 0; sub < 2; ++sub) {
    const int lr = sub * 16 + l16;
    f32x4 acc = f32x4{0.f, 0.f, 0.f, 0.f};
#pragma unroll
    for (int kc = 0; kc < KSTEPS; ++kc) {
      const short8 xf = *reinterpret_cast<const short8*>(
          &xt[(lr * 256 + kc * 32 + 8 * g) ^ ((lr & 7) << 3)]);
      acc = __builtin_amdgcn_mfma_f32_16x16x32_bf16(wf[kc], xf, acc, 0, 0, 0);
    }
    const float f0 = fmaxf(acc[0] + bev.x, 0.f);
    const float f1 = fmaxf(acc[1] + bev.y, 0.f);
    const float f2 = fmaxf(acc[2] + bev.z, 0.f);
    const float f3 = fmaxf(acc[3] + bev.w, 0.f);
    *reinterpret_cast<float4*>(
        &featOut[(size_t)(rbase + lr) * 64 + 16 * w + 4 * g]) =
        make_float4(f0, f1, f2, f3);
    u32 p0, p1;
    asm("v_cvt_pk_bf16_f32 %0, %1, %2" : "=v"(p0) : "v"(f0), "v"(f1));
    asm("v_cvt_pk_bf16_f32 %0, %1, %2" : "=v"(p1) : "v"(f2), "v"(f3));
    *reinterpret_cast<uint2*>(&ft[(lr * 64 + 16 * w + 4 * g) ^
                                  ((lr & 7) << 3)]) = make_uint2(p0, p1);
  }
  __syncthreads();

  // ---- Q/K/V = Feat @ W* + b* (Q scaled by 1/8) ----
  const float4 bqv = *reinterpret_cast<const float4*>(&bq[16 * w + 4 * g]);
  const float4 bkv = *reinterpret_cast<const float4*>(&bk[16 * w + 4 * g]);
  const float4 bvv = *reinterpret_cast<const float4*>(&bv[16 * w + 4 * g]);
#pragma unroll
  for (int sub = 0; sub < 2; ++sub) {
    const int lr = sub * 16 + l16;
    const short8 xf0 = *reinterpret_cast<const short8*>(
        &ft[(lr * 64 + 0 * 32 + 8 * g) ^ ((lr & 7) << 3)]);
    const short8 xf1 = *reinterpret_cast<const short8*>(
        &ft[(lr * 64 + 1 * 32 + 8 * g) ^ ((lr & 7) << 3)]);
    f32x4 aq = f32x4{0.f, 0.f, 0.f, 0.f};
    f32x4 ak = f32x4{0.f, 0.f, 0.f, 0.f};
    f32x4 av = f32x4{0.f, 0.f, 0.f, 0.f};
    aq = __builtin_amdgcn_mfma_f32_16x16x32_bf16(qf[0], xf0, aq, 0, 0, 0);
    aq = __builtin_amdgcn_mfma_f32_16x16x32_bf16(qf[1], xf1, aq, 0, 0, 0);
    ak = __builtin_amdgcn_mfma_f32_16x16x32_bf16(kf[0], xf0, ak, 0, 0, 0);
    ak = __builtin_amdgcn_mfma_f32_16x16x32_bf16(kf[1], xf1, ak, 0, 0, 0);
    av = __builtin_amdgcn_mfma_f32_16x16x32_bf16(vf[0], xf0, av, 0, 0, 0);
    av = __builtin_amdgcn_mfma_f32_16x16x32_bf16(vf[1], xf1, av, 0, 0, 0);
    const size_t off = (size_t)(rbase + lr) * 64 + 16 * w + 4 * g;
    u32 a0, a1;
    asm("v_cvt_pk_bf16_f32 %0, %1, %2"
        : "=v"(a0)
        : "v"((aq[0] + bqv.x) * 0.125f), "v"((aq[1] + bqv.y) * 0.125f));
    asm("v_cvt_pk_bf16_f32 %0, %1, %2"
        : "=v"(a1)
        : "v"((aq[2] + bqv.z) * 0.125f), "v"((aq[3] + bqv.w) * 0.125f));
    *reinterpret_cast<uint2*>(Qout + off) = make_uint2(a0, a1);
    asm("v_cvt_pk_bf16_f32 %0, %1, %2"
        : "=v"(a0)
        : "v"(ak[0] + bkv.x), "v"(ak[1] + bkv.y));
    asm("v_cvt_pk_bf16_f32 %0, %1, %2"
        : "=v"(a1)
        : "v"(ak[2] + bkv.z), "v"(ak[3] + bkv.w));
    *reinterpret_cast<uint2*>(Kout + off) = make_uint2(a0, a1);
    asm("v_cvt_pk_bf16_f32 %0, %1, %2"
        : "=v"(a0)
        : "v"(av[0] + bvv.x), "v"(av[1] + bvv.y));
    asm("v_cvt_pk_bf16_f32 %0, %1, %2"
        : "=v"(a1)
        : "v"(av[2] + bvv.z), "v"(av[3] + bvv.w));
    *reinterpret_cast<uint2*>(Vout + off) = make_uint2(a0, a1);
  }
}

// blocks [0,256) nir, [256,512) libs; 32 rows/block
__global__ __launch_bounds__(256) void extract_fused_kernel(
    const float* __restrict__ nir_x, const float* __restrict__ libs_x,
    const float* __restrict__ n_lng, const float* __restrict__ n_lnb,
    const float* __restrict__ n_We, const float* __restrict__ n_be,
    const float* __restrict__ l_lng, const float* __restrict__ l_lnb,
    const float* __restrict__ l_We, const float* __restrict__ l_be,
    const float* __restrict__ q_ln_w, const float* __restrict__ q_ln_b,
    const float* __restrict__ k_ln_w, const float* __restrict__ k_ln_b,
    const float* __restrict__ v_ln_w, const float* __restrict__ v_ln_b,
    const float* __restrict__ q_nl_w, const float* __restrict__ q_nl_b,
    const float* __restrict__ k_nl_w, const float* __restrict__ k_nl_b,
    const float* __restrict__ v_nl_w, const float* __restrict__ v_nl_b,
    float* __restrict__ f_nir, float* __restrict__ f_libs,
    u16* __restrict__ Qb_nir, u16* __restrict__ Kb_nir,
    u16* __restrict__ Vb_nir, u16* __restrict__ Qb_libs,
    u16* __restrict__ Kb_libs, u16* __restrict__ Vb_libs) {
  __shared__ __align__(16) u16 xt[32 * 256];
  __shared__ __align__(16) u16 ft[32 * 64];
  if (blockIdx.x < 256) {
    // nir: Q uses q_nl, K/V use *_ln; K=215 -> 7 ksteps (pad 224)
    extract_mfma_body<215, 7>(blockIdx.x * 32, xt, ft, nir_x, n_lng, n_lnb,
                              n_We, n_be, q_nl_w, q_nl_b, k_ln_w, k_ln_b,
                              v_ln_w, v_ln_b, f_nir, Qb_nir, Kb_nir, Vb_nir);
  } else {
    // libs: Q uses q_ln, K/V use *_nl; K=244 -> 8 ksteps (pad 256)
    extract_mfma_body<244, 8>((blockIdx.x - 256) * 32, xt, ft, libs_x, l_lng,
                              l_lnb, l_We, l_be, q_ln_w, q_ln_b, k_nl_w,
                              k_nl_b, v_nl_w, v_nl_b, f_libs, Qb_libs,
                              Kb_libs, Vb_libs);
  }
}

// ---------------- flash attention (R12-proven, byte-identical) ----------------
__global__ __launch_bounds__(256, 2) void attn_mfma_kernel(
    const u16* __restrict__ Qb0, const u16* __restrict__ Kb0,
    const u16* __restrict__ Vb0, const u16* __restrict__ Qb1,
    const u16* __restrict__ Kb1, const u16* __restrict__ Vb1,
    u16* __restrict__ Opart, float* __restrict__ lpart) {
  __shared__ __align__(16) u16 lds_k[4096];    // [kv][d] ^ ((kv&7)<<3)
  __shared__ __align__(16) u16 lds_vt[4096];   // [d][kv] ^ (((d>>1)&7)<<3)
  __shared__ __align__(16) u32 lds_p[4][544];  // per-wave [16 q][34], reused per sub

  const int bid = blockIdx.x;
  const int split = bid & 7;
  const int dir = (bid >> 3) & 1;
  const int qt = bid >> 4;
  const int slab = dir * 8 + split;
  const int kvbase = split * 1024;

  const u16* Q = dir ? Qb1 : Qb0;
  const u16* K = dir ? Kb1 : Kb0;
  const u16* V = dir ? Vb1 : Vb0;

  const int t = threadIdx.x;
  const int w = t >> 6;
  const int lane = t & 63;
  const int g = lane >> 4;
  const int l16 = lane & 15;
  const int qblk = qt * 256 + w * 64;

  short8 qa[4][2];
#pragma unroll
  for (int sub = 0; sub < 4; ++sub)
#pragma unroll
    for (int c = 0; c < 2; ++c)
      qa[sub][c] = *reinterpret_cast<const short8*>(
          Q + (size_t)(qblk + sub * 16 + l16) * 64 + 32 * c + 8 * g);

  f32x4 oacc[4][4];
#pragma unroll
  for (int sub = 0; sub < 4; ++sub)
#pragma unroll
    for (int db = 0; db < 4; ++db) oacc[sub][db] = f32x4{0.f, 0.f, 0.f, 0.f};
  float l_run[4] = {0.f, 0.f, 0.f, 0.f};

  const int kv0 = (t >> 4) << 2;
  const int d0 = (t & 15) << 2;
  ushort4 kh[4], vh[4];

#define LOADT(tile_)                                                          \
  {                                                                           \
    _Pragma("unroll") for (int j = 0; j < 4; ++j) {                           \
      const size_t off = ((size_t)(kvbase + (tile_)*64 + kv0 + j)) * 64 + d0; \
      kh[j] = *reinterpret_cast<const ushort4*>(K + off);                     \
      vh[j] = *reinterpret_cast<const ushort4*>(V + off);                     \
    }                                                                         \
  }

#define STORET()                                                              \
  {                                                                           \
    _Pragma("unroll") for (int j = 0; j < 4; ++j) {                           \
      const int row = kv0 + j;                                                \
      *reinterpret_cast<ushort4*>(                                            \
          &lds_k[(row * 64 + d0) ^ ((row & 7) << 3)]) = kh[j];                \
    }                                                                         \
    _Pragma("unroll") for (int i = 0; i < 4; ++i) {                           \
      const int row = d0 + i;                                                 \
      ushort4 vt;                                                             \
      vt.x = (&vh[0].x)[i];                                                   \
      vt.y = (&vh[1].x)[i];                                                   \
      vt.z = (&vh[2].x)[i];                                                   \
      vt.w = (&vh[3].x)[i];                                                   \
      *reinterpret_cast<ushort4*>(                                            \
          &lds_vt[(row * 64 + kv0) ^ (((row >> 1) & 7) << 3)]) = vt;          \
    }                                                                         \
  }

  LOADT(0);
  STORET();
  LOADT(1);
  asm volatile("s_waitcnt lgkmcnt(0)" ::: "memory");
  __builtin_amdgcn_s_barrier();
  asm volatile("" ::: "memory");

  for (int tile = 0; tile < 16; ++tile) {
    f32x4 sacc[4][4];
#pragma unroll
    for (int sub = 0; sub < 4; ++sub)
#pragma unroll
      for (int kb = 0; kb < 4; ++kb) sacc[sub][kb] = f32x4{0.f, 0.f, 0.f, 0.f};
#pragma unroll
    for (int c = 0; c < 2; ++c) {
#pragma unroll
      for (int kb = 0; kb < 4; ++kb) {
        const int row = 16 * kb + l16;
        const int idx = (row * 64 + 32 * c + 8 * g) ^ ((row & 7) << 3);
        const short8 kfrag = *reinterpret_cast<const short8*>(&lds_k[idx]);
#pragma unroll
        for (int sub = 0; sub < 4; ++sub)
          sacc[sub][kb] = __builtin_amdgcn_mfma_f32_16x16x32_bf16(
              kfrag, qa[sub][c], sacc[sub][kb], 0, 0, 0);
      }
    }

    short8 pB[4][2];
#pragma unroll
    for (int sub = 0; sub < 4; ++sub) {
      float lsub = 0.f;
#pragma unroll
      for (int kb = 0; kb < 4; ++kb) {
        const float p0 = __expf(sacc[sub][kb][0]);
        const float p1 = __expf(sacc[sub][kb][1]);
        const float p2 = __expf(sacc[sub][kb][2]);
        const float p3 = __expf(sacc[sub][kb][3]);
        lsub += (p0 + p1) + (p2 + p3);
        u32 w0, w1;
        asm("v_cvt_pk_bf16_f32 %0, %1, %2" : "=v"(w0) : "v"(p0), "v"(p1));
        asm("v_cvt_pk_bf16_f32 %0, %1, %2" : "=v"(w1) : "v"(p2), "v"(p3));
        *reinterpret_cast<uint2*>(&lds_p[w][l16 * 34 + 8 * kb + 2 * g]) =
            make_uint2(w0, w1);
      }
      l_run[sub] += lsub;
      asm volatile("" ::: "memory");
#pragma unroll
      for (int c = 0; c < 2; ++c) {
        const int base = l16 * 34 + 16 * c + 4 * g;
        const uint2 a = *reinterpret_cast<const uint2*>(&lds_p[w][base]);
        const uint2 bb = *reinterpret_cast<const uint2*>(&lds_p[w][base + 2]);
        u32 q4[4] = {a.x, a.y, bb.x, bb.y};
        pB[sub][c] = __builtin_bit_cast(short8, *(ulonglong2*)q4);
      }
      asm volatile("" ::: "memory");
    }

#pragma unroll
    for (int c = 0; c < 2; ++c) {
#pragma unroll
      for (int db = 0; db < 4; ++db) {
        const int row = 16 * db + l16;
        const int idx = (row * 64 + 32 * c + 8 * g) ^ (((row >> 1) & 7) << 3);
        const short8 vfrag = *reinterpret_cast<const short8*>(&lds_vt[idx]);
#pragma unroll
        for (int sub = 0; sub < 4; ++sub)
          oacc[sub][db] = __builtin_amdgcn_mfma_f32_16x16x32_bf16(
              vfrag, pB[sub][c], oacc[sub][db], 0, 0, 0);
      }
    }

    asm volatile("s_waitcnt lgkmcnt(0)" ::: "memory");
    __builtin_amdgcn_s_barrier();
    asm volatile("" ::: "memory");
    if (tile < 15) {
      STORET();
      if (tile < 14) LOADT(tile + 2);
    }
    asm volatile("s_waitcnt lgkmcnt(0)" ::: "memory");
    __builtin_amdgcn_s_barrier();
    asm volatile("" ::: "memory");
  }

  const size_t S = (size_t)8192 * 64;
#pragma unroll
  for (int sub = 0; sub < 4; ++sub) {
    const int q = qblk + sub * 16 + l16;
#pragma unroll
    for (int db = 0; db < 4; ++db) {
      u32 w0, w1;
      asm("v_cvt_pk_bf16_f32 %0, %1, %2"
          : "=v"(w0)
          : "v"(oacc[sub][db][0]), "v"(oacc[sub][db][1]));
      asm("v_cvt_pk_bf16_f32 %0, %1, %2"
          : "=v"(w1)
          : "v"(oacc[sub][db][2]), "v"(oacc[sub][db][3]));
      *reinterpret_cast<uint2*>(Opart + (size_t)slab * S + (size_t)q * 64 +
                                16 * db + 4 * g) = make_uint2(w0, w1);
    }
    float lv = l_run[sub];
    lv += __shfl_xor(lv, 16, 64);
    lv += __shfl_xor(lv, 32, 64);
    if (g == 0) lpart[slab * 8192 + q] = lv;
  }
#undef LOADT
#undef STORET
}

// ---------------- post (R12-proven, byte-identical) ----------------
__global__ __launch_bounds__(256) void post_kernel(
    const u16* __restrict__ Opart, const float* __restrict__ lpart,
    const float* __restrict__ nirF, const float* __restrict__ libsF,
    const float* __restrict__ ln1g, const float* __restrict__ ln1b,
    const float* __restrict__ fc1w, const float* __restrict__ fc1b,
    const float* __restrict__ ln2g, const float* __restrict__ ln2b,
    const float* __restrict__ fc2w, const float* __restrict__ fc2b,
    const float* __restrict__ ln0g, const float* __restrict__ ln0b,
    const float* __restrict__ gatew, const float* __restrict__ gateb,
    const float* __restrict__ ln3g, const float* __restrict__ ln3b,
    const float* __restrict__ fc3w, const float* __restrict__ fc3b,
    const float* __restrict__ ln4g, const float* __restrict__ ln4b,
    const float* __restrict__ fc4w, const float* __restrict__ fc4b,
    float* __restrict__ out) {
  __shared__ u16 FC1[4096], FC2[4096], FC3[2048];
  __shared__ u16 GW[8192];
  __shared__ float rbuf[4][128];
  const int t = threadIdx.x, w = t >> 6, lane = t & 63;
  const size_t S = (size_t)8192 * 64;
  for (int i = t; i < 4096; i += 256) {
    FC1[i] = f2bf(fc1w[i]);
    FC2[i] = f2bf(fc2w[i]);
  }
  for (int i = t; i < 2048; i += 256) FC3[i] = f2bf(fc3w[i]);
  for (int i = t; i < 8192; i += 256) GW[i] = f2bf(gatew[i]);
  __syncthreads();
#pragma unroll
  for (int rr = 0; rr < 2; ++rr) {
    const int r = blockIdx.x * 8 + rr * 4 + w;
    const size_t ro = (size_t)r * 64;

    float a1 = 0.f, a2 = 0.f, l1 = 0.f, l2 = 0.f;
#pragma unroll
    for (int s = 0; s < 8; ++s) {
      a1 += bf2f(Opart[(size_t)s * S + ro + lane]);
      a2 += bf2f(Opart[(size_t)(8 + s) * S + ro + lane]);
      l1 += lpart[s * 8192 + r];
      l2 += lpart[(8 + s) * 8192 + r];
    }
    a1 /= l1;  // attn_libs_to_nir
    a2 /= l2;  // attn_nir_to_libs

    const float nv = nirF[ro + lane], lv_ = libsF[ro + lane];

    float s1 = wave_sum64(a2), ss1 = wave_sum64(a2 * a2);
    float mean = s1 * (1.f / 64);
    float rstd = rsqrtf(ss1 * (1.f / 64) - mean * mean + LN_EPS);
    rbuf[w][lane] = (a2 - mean) * rstd * ln1g[lane] + ln1b[lane];
    __syncthreads();
    float o1 = fc1b[lane];
#pragma unroll 8
    for (int i = 0; i < 64; ++i)
      o1 = fmaf(rbuf[w][i], bf2f(FC1[i * 64 + lane]), o1);
    const float out1 = fmaxf(o1, 0.f) + lv_;
    __syncthreads();

    s1 = wave_sum64(a1);
    ss1 = wave_sum64(a1 * a1);
    mean = s1 * (1.f / 64);
    rstd = rsqrtf(ss1 * (1.f / 64) - mean * mean + LN_EPS);
    rbuf[w][lane] = (a1 - mean) * rstd * ln2g[lane] + ln2b[lane];
    __syncthreads();
    float o2 = fc2b[lane];
#pragma unroll 8
    for (int i = 0; i < 64; ++i)
      o2 = fmaf(rbuf[w][i], bf2f(FC2[i * 64 + lane]), o2);
    const float out2 = fmaxf(o2, 0.f) + nv;
    __syncthreads();

    s1 = wave_sum64(out1 + out2);
    ss1 = wave_sum64(out1 * out1 + out2 * out2);
    mean = s1 * (1.f / 128);
    rstd = rsqrtf(ss1 * (1.f / 128) - mean * mean + LN_EPS);
    rbuf[w][lane] = (out1 - mean) * rstd * ln0g[lane] + ln0b[lane];
    rbuf[w][64 + lane] =
        (out2 - mean) * rstd * ln0g[64 + lane] + ln0b[64 + lane];
    __syncthreads();
    float gg = gateb[lane];
#pragma unroll 8
    for (int i = 0; i < 128; ++i)
      gg = fmaf(rbuf[w][i], bf2f(GW[i * 64 + lane]), gg);
    gg = 1.f / (1.f + __expf(-gg));
    const float fused = gg * out1 + (1.f - gg) * out2;
    __syncthreads();

    s1 = wave_sum64(fused);
    ss1 = wave_sum64(fused * fused);
    mean = s1 * (1.f / 64);
    rstd = rsqrtf(ss1 * (1.f / 64) - mean * mean + LN_EPS);
    rbuf[w][lane] = (fused - mean) * rstd * ln3g[lane] + ln3b[lane];
    __syncthreads();
    if (lane < 32) {
      float h = fc3b[lane];
#pragma unroll 8
      for (int i = 0; i < 64; ++i)
        h = fmaf(rbuf[w][i], bf2f(FC3[i * 32 + lane]), h);
      h = fmaxf(h, 0.f);
      const float hs = grp32_sum(h), hss = grp32_sum(h * h);
      const float hm = hs * (1.f / 32);
      const float hr = rsqrtf(hss * (1.f / 32) - hm * hm + LN_EPS);
      const float y4 = (h - hm) * hr * ln4g[lane] + ln4b[lane];
      const float part = grp32_sum(y4 * fc4w[lane]);
      if (lane == 0) out[r] = part + fc4b[0];
    }
    __syncthreads();
  }
}

extern "C" void kernel_launch(void* const* d_in, const int* in_sizes, int n_in,
                              void* d_out, int out_size, void* d_ws,
                              size_t ws_size, hipStream_t stream) {
  const float* nir_data = (const float*)d_in[0];
  const float* libs_data = (const float*)d_in[1];
  const float* nir_ln_g = (const float*)d_in[2];
  const float* nir_ln_b = (const float*)d_in[3];
  const float* nir_w = (const float*)d_in[4];
  const float* nir_b = (const float*)d_in[5];
  const float* libs_ln_g = (const float*)d_in[6];
  const float* libs_ln_b = (const float*)d_in[7];
  const float* libs_w = (const float*)d_in[8];
  const float* libs_b = (const float*)d_in[9];
  const float* q_ln_w = (const float*)d_in[10];
  const float* q_ln_b = (const float*)d_in[11];
  const float* k_ln_w = (const float*)d_in[12];
  const float* k_ln_b = (const float*)d_in[13];
  const float* v_ln_w = (const float*)d_in[14];
  const float* v_ln_b = (const float*)d_in[15];
  const float* q_nl_w = (const float*)d_in[16];
  const float* q_nl_b = (const float*)d_in[17];
  const float* k_nl_w = (const float*)d_in[18];
  const float* k_nl_b = (const float*)d_in[19];
  const float* v_nl_w = (const float*)d_in[20];
  const float* v_nl_b = (const float*)d_in[21];
  const float* ln1_g = (const float*)d_in[22];
  const float* ln1_b = (const float*)d_in[23];
  const float* fc1_w = (const float*)d_in[24];
  const float* fc1_b = (const float*)d_in[25];
  const float* ln2_g = (const float*)d_in[26];
  const float* ln2_b = (const float*)d_in[27];
  const float* fc2_w = (const float*)d_in[28];
  const float* fc2_b = (const float*)d_in[29];
  const float* ln0_g = (const float*)d_in[30];
  const float* ln0_b = (const float*)d_in[31];
  const float* gate_w = (const float*)d_in[32];
  const float* gate_b = (const float*)d_in[33];
  const float* ln3_g = (const float*)d_in[34];
  const float* ln3_b = (const float*)d_in[35];
  const float* fc3_w = (const float*)d_in[36];
  const float* fc3_b = (const float*)d_in[37];
  const float* ln4_g = (const float*)d_in[38];
  const float* ln4_b = (const float*)d_in[39];
  const float* fc4_w = (const float*)d_in[40];
  const float* fc4_b = (const float*)d_in[41];

  const size_t S = (size_t)8192 * 64;
  u16* ub = (u16*)d_ws;
  u16* Qb_nir = ub + 0 * S;
  u16* Kb_nir = ub + 1 * S;
  u16* Vb_nir = ub + 2 * S;
  u16* Qb_libs = ub + 3 * S;
  u16* Kb_libs = ub + 4 * S;
  u16* Vb_libs = ub + 5 * S;
  u16* OpartU = ub + 6 * S;  // 16 slabs bf16 (2 dirs x 8 splits)
  float* fp = (float*)(ub + 22 * S);
  float* f_nir = fp + 0 * S;
  float* f_libs = fp + 1 * S;
  float* lpart = fp + 2 * S;  // 16 x 8192

  extract_fused_kernel<<<512, 256, 0, stream>>>(
      nir_data, libs_data, nir_ln_g, nir_ln_b, nir_w, nir_b, libs_ln_g,
      libs_ln_b, libs_w, libs_b, q_ln_w, q_ln_b, k_ln_w, k_ln_b, v_ln_w,
      v_ln_b, q_nl_w, q_nl_b, k_nl_w, k_nl_b, v_nl_w, v_nl_b, f_nir, f_libs,
      Qb_nir, Kb_nir, Vb_nir, Qb_libs, Kb_libs, Vb_libs);

  // dir0: Q_libs x K/V_nir ; dir1: Q_nir x K/V_libs
  attn_mfma_kernel<<<512, 256, 0, stream>>>(Qb_libs, Kb_nir, Vb_nir, Qb_nir,
                                            Kb_libs, Vb_libs, OpartU, lpart);

  post_kernel<<<1024, 256, 0, stream>>>(
      OpartU, lpart, f_nir, f_libs, ln1_g, ln1_b, fc1_w, fc1_b, ln2_g, ln2_b,
      fc2_w, fc2_b, ln0_g, ln0_b, gate_w, gate_b, ln3_g, ln3_b, fc3_w, fc3_b,
      ln4_g, ln4_b, fc4_w, fc4_b, (float*)d_out);
}

// Round 16
// 93.405 us; speedup vs baseline: 1.4072x; 1.0085x over previous
//
#include <hip/hip_runtime.h>
#include <hip/hip_bf16.h>
#include <math.h>

#define LN_EPS 1e-5f

typedef __attribute__((ext_vector_type(8))) short short8;
typedef __attribute__((ext_vector_type(4))) float f32x4;
typedef unsigned short u16;
typedef unsigned int u32;

__device__ __forceinline__ u16 f2bf(float f) {
  __hip_bfloat16 h = __float2bfloat16(f);
  return __builtin_bit_cast(u16, h);
}
__device__ __forceinline__ float bf2f(u16 u) {
  u32 x = ((u32)u) << 16;
  return __builtin_bit_cast(float, x);
}

// ---------------- wave reduction helpers ----------------
__device__ __forceinline__ float wave_sum64(float v) {
#pragma unroll
  for (int m = 1; m <= 32; m <<= 1) v += __shfl_xor(v, m, 64);
  return v;
}
__device__ __forceinline__ float grp32_sum(float v) {
#pragma unroll
  for (int m = 1; m <= 16; m <<= 1) v += __shfl_xor(v, m, 64);
  return v;
}

// ---------------- extractor, MFMA version (R14-proven, byte-identical) ----------------
template <int DM, int KSTEPS>
__device__ __forceinline__ void extract_mfma_body(
    int rbase, u16* xt, u16* ft, const float* __restrict__ xin,
    const float* __restrict__ lng, const float* __restrict__ lnb,
    const float* __restrict__ We, const float* __restrict__ be,
    const float* __restrict__ Wq, const float* __restrict__ bq,
    const float* __restrict__ Wk, const float* __restrict__ bk,
    const float* __restrict__ Wv, const float* __restrict__ bv,
    float* __restrict__ featOut, u16* __restrict__ Qout,
    u16* __restrict__ Kout, u16* __restrict__ Vout) {
  const int t = threadIdx.x, w = t >> 6, lane = t & 63;
  const int g = lane >> 4, l16 = lane & 15;
  const int c = 16 * w + l16;  // A-frag row = this lane's weight column

  // ---- A-fragments: gather f32 weights -> bf16 regs (issued early) ----
  short8 wf[KSTEPS];
#pragma unroll
  for (int kc = 0; kc < KSTEPS; ++kc) {
    short8 f;
#pragma unroll
    for (int i = 0; i < 8; ++i) {
      const int k = kc * 32 + 8 * g + i;
      f[i] = (short)((k < DM) ? f2bf(We[(size_t)k * 64 + c]) : (u16)0);
    }
    wf[kc] = f;
  }
  short8 qf[2], kf[2], vf[2];
#pragma unroll
  for (int kc = 0; kc < 2; ++kc) {
    short8 fq, fk, fv;
#pragma unroll
    for (int i = 0; i < 8; ++i) {
      const int k = kc * 32 + 8 * g + i;
      fq[i] = (short)f2bf(Wq[k * 64 + c]);
      fk[i] = (short)f2bf(Wk[k * 64 + c]);
      fv[i] = (short)f2bf(Wv[k * 64 + c]);
    }
    qf[kc] = fq;
    kf[kc] = fk;
    vf[kc] = fv;
  }

  // ---- LN: 8 rows/wave (4 passes x 2-row ILP), bf16 swizzled xt ----
#pragma unroll
  for (int pp = 0; pp < 4; ++pp) {
    const int lrA = 8 * w + pp * 2;
    const int lrB = lrA + 1;
    const float* xA = xin + (size_t)(rbase + lrA) * DM;
    const float* xB = xin + (size_t)(rbase + lrB) * DM;
    float xrA[4], xrB[4];
    float sA = 0.f, ssA = 0.f, sB = 0.f, ssB = 0.f;
#pragma unroll
    for (int u = 0; u < 4; ++u) {
      const int idx = u * 64 + lane;
      const float vA = (idx < DM) ? xA[idx] : 0.f;
      const float vB = (idx < DM) ? xB[idx] : 0.f;
      xrA[u] = vA;
      xrB[u] = vB;
      sA += vA;
      ssA += vA * vA;
      sB += vB;
      ssB += vB * vB;
    }
    sA = wave_sum64(sA);
    ssA = wave_sum64(ssA);
    sB = wave_sum64(sB);
    ssB = wave_sum64(ssB);
    const float mA = sA / (float)DM;
    const float rAs = rsqrtf(ssA / (float)DM - mA * mA + LN_EPS);
    const float mB = sB / (float)DM;
    const float rBs = rsqrtf(ssB / (float)DM - mB * mB + LN_EPS);
#pragma unroll
    for (int u = 0; u < 4; ++u) {
      const int idx = u * 64 + lane;
      float yA = 0.f, yB = 0.f;
      if (idx < DM) {
        const float gg = lng[idx], bb = lnb[idx];
        yA = (xrA[u] - mA) * rAs * gg + bb;
        yB = (xrB[u] - mB) * rBs * gg + bb;
      }
      xt[(lrA * 256 + idx) ^ ((lrA & 7) << 3)] = f2bf(yA);
      xt[(lrB * 256 + idx) ^ ((lrB & 7) << 3)] = f2bf(yB);
    }
  }
  __syncthreads();

  // ---- Feat = LN(x) @ We + be, ReLU -> f32 featOut + bf16 ft ----
  const float4 bev = *reinterpret_cast<const float4*>(&be[16 * w + 4 * g]);
#pragma unroll
  for (int sub = 0; sub < 2; ++sub) {
    const int lr = sub * 16 + l16;
    f32x4 acc = f32x4{0.f, 0.f, 0.f, 0.f};
#pragma unroll
    for (int kc = 0; kc < KSTEPS; ++kc) {
      const short8 xf = *reinterpret_cast<const short8*>(
          &xt[(lr * 256 + kc * 32 + 8 * g) ^ ((lr & 7) << 3)]);
      acc = __builtin_amdgcn_mfma_f32_16x16x32_bf16(wf[kc], xf, acc, 0, 0, 0);
    }
    const float f0 = fmaxf(acc[0] + bev.x, 0.f);
    const float f1 = fmaxf(acc[1] + bev.y, 0.f);
    const float f2 = fmaxf(acc[2] + bev.z, 0.f);
    const float f3 = fmaxf(acc[3] + bev.w, 0.f);
    *reinterpret_cast<float4*>(
        &featOut[(size_t)(rbase + lr) * 64 + 16 * w + 4 * g]) =
        make_float4(f0, f1, f2, f3);
    u32 p0, p1;
    asm("v_cvt_pk_bf16_f32 %0, %1, %2" : "=v"(p0) : "v"(f0), "v"(f1));
    asm("v_cvt_pk_bf16_f32 %0, %1, %2" : "=v"(p1) : "v"(f2), "v"(f3));
    *reinterpret_cast<uint2*>(&ft[(lr * 64 + 16 * w + 4 * g) ^
                                  ((lr & 7) << 3)]) = make_uint2(p0, p1);
  }
  __syncthreads();

  // ---- Q/K/V = Feat @ W* + b* (Q scaled by 1/8) ----
  const float4 bqv = *reinterpret_cast<const float4*>(&bq[16 * w + 4 * g]);
  const float4 bkv = *reinterpret_cast<const float4*>(&bk[16 * w + 4 * g]);
  const float4 bvv = *reinterpret_cast<const float4*>(&bv[16 * w + 4 * g]);
#pragma unroll
  for (int sub = 0; sub < 2; ++sub) {
    const int lr = sub * 16 + l16;
    const short8 xf0 = *reinterpret_cast<const short8*>(
        &ft[(lr * 64 + 0 * 32 + 8 * g) ^ ((lr & 7) << 3)]);
    const short8 xf1 = *reinterpret_cast<const short8*>(
        &ft[(lr * 64 + 1 * 32 + 8 * g) ^ ((lr & 7) << 3)]);
    f32x4 aq = f32x4{0.f, 0.f, 0.f, 0.f};
    f32x4 ak = f32x4{0.f, 0.f, 0.f, 0.f};
    f32x4 av = f32x4{0.f, 0.f, 0.f, 0.f};
    aq = __builtin_amdgcn_mfma_f32_16x16x32_bf16(qf[0], xf0, aq, 0, 0, 0);
    aq = __builtin_amdgcn_mfma_f32_16x16x32_bf16(qf[1], xf1, aq, 0, 0, 0);
    ak = __builtin_amdgcn_mfma_f32_16x16x32_bf16(kf[0], xf0, ak, 0, 0, 0);
    ak = __builtin_amdgcn_mfma_f32_16x16x32_bf16(kf[1], xf1, ak, 0, 0, 0);
    av = __builtin_amdgcn_mfma_f32_16x16x32_bf16(vf[0], xf0, av, 0, 0, 0);
    av = __builtin_amdgcn_mfma_f32_16x16x32_bf16(vf[1], xf1, av, 0, 0, 0);
    const size_t off = (size_t)(rbase + lr) * 64 + 16 * w + 4 * g;
    u32 a0, a1;
    asm("v_cvt_pk_bf16_f32 %0, %1, %2"
        : "=v"(a0)
        : "v"((aq[0] + bqv.x) * 0.125f), "v"((aq[1] + bqv.y) * 0.125f));
    asm("v_cvt_pk_bf16_f32 %0, %1, %2"
        : "=v"(a1)
        : "v"((aq[2] + bqv.z) * 0.125f), "v"((aq[3] + bqv.w) * 0.125f));
    *reinterpret_cast<uint2*>(Qout + off) = make_uint2(a0, a1);
    asm("v_cvt_pk_bf16_f32 %0, %1, %2"
        : "=v"(a0)
        : "v"(ak[0] + bkv.x), "v"(ak[1] + bkv.y));
    asm("v_cvt_pk_bf16_f32 %0, %1, %2"
        : "=v"(a1)
        : "v"(ak[2] + bkv.z), "v"(ak[3] + bkv.w));
    *reinterpret_cast<uint2*>(Kout + off) = make_uint2(a0, a1);
    asm("v_cvt_pk_bf16_f32 %0, %1, %2"
        : "=v"(a0)
        : "v"(av[0] + bvv.x), "v"(av[1] + bvv.y));
    asm("v_cvt_pk_bf16_f32 %0, %1, %2"
        : "=v"(a1)
        : "v"(av[2] + bvv.z), "v"(av[3] + bvv.w));
    *reinterpret_cast<uint2*>(Vout + off) = make_uint2(a0, a1);
  }
}

// blocks [0,256) nir, [256,512) libs; 32 rows/block
__global__ __launch_bounds__(256) void extract_fused_kernel(
    const float* __restrict__ nir_x, const float* __restrict__ libs_x,
    const float* __restrict__ n_lng, const float* __restrict__ n_lnb,
    const float* __restrict__ n_We, const float* __restrict__ n_be,
    const float* __restrict__ l_lng, const float* __restrict__ l_lnb,
    const float* __restrict__ l_We, const float* __restrict__ l_be,
    const float* __restrict__ q_ln_w, const float* __restrict__ q_ln_b,
    const float* __restrict__ k_ln_w, const float* __restrict__ k_ln_b,
    const float* __restrict__ v_ln_w, const float* __restrict__ v_ln_b,
    const float* __restrict__ q_nl_w, const float* __restrict__ q_nl_b,
    const float* __restrict__ k_nl_w, const float* __restrict__ k_nl_b,
    const float* __restrict__ v_nl_w, const float* __restrict__ v_nl_b,
    float* __restrict__ f_nir, float* __restrict__ f_libs,
    u16* __restrict__ Qb_nir, u16* __restrict__ Kb_nir,
    u16* __restrict__ Vb_nir, u16* __restrict__ Qb_libs,
    u16* __restrict__ Kb_libs, u16* __restrict__ Vb_libs) {
  __shared__ __align__(16) u16 xt[32 * 256];
  __shared__ __align__(16) u16 ft[32 * 64];
  if (blockIdx.x < 256) {
    extract_mfma_body<215, 7>(blockIdx.x * 32, xt, ft, nir_x, n_lng, n_lnb,
                              n_We, n_be, q_nl_w, q_nl_b, k_ln_w, k_ln_b,
                              v_ln_w, v_ln_b, f_nir, Qb_nir, Kb_nir, Vb_nir);
  } else {
    extract_mfma_body<244, 8>((blockIdx.x - 256) * 32, xt, ft, libs_x, l_lng,
                              l_lnb, l_We, l_be, q_ln_w, q_ln_b, k_nl_w,
                              k_nl_b, v_nl_w, v_nl_b, f_libs, Qb_libs,
                              Kb_libs, Vb_libs);
  }
}

// ---------------- flash attention (R14-proven, byte-identical: single
// buffer, two barriers per tile; the R15 dbuf experiment failed and is
// permanently abandoned) ----------------
__global__ __launch_bounds__(256, 2) void attn_mfma_kernel(
    const u16* __restrict__ Qb0, const u16* __restrict__ Kb0,
    const u16* __restrict__ Vb0, const u16* __restrict__ Qb1,
    const u16* __restrict__ Kb1, const u16* __restrict__ Vb1,
    u16* __restrict__ Opart, float* __restrict__ lpart) {
  __shared__ __align__(16) u16 lds_k[4096];    // [kv][d] ^ ((kv&7)<<3)
  __shared__ __align__(16) u16 lds_vt[4096];   // [d][kv] ^ (((d>>1)&7)<<3)
  __shared__ __align__(16) u32 lds_p[4][544];  // per-wave [16 q][34], reused per sub

  const int bid = blockIdx.x;
  const int split = bid & 7;
  const int dir = (bid >> 3) & 1;
  const int qt = bid >> 4;
  const int slab = dir * 8 + split;
  const int kvbase = split * 1024;

  const u16* Q = dir ? Qb1 : Qb0;
  const u16* K = dir ? Kb1 : Kb0;
  const u16* V = dir ? Vb1 : Vb0;

  const int t = threadIdx.x;
  const int w = t >> 6;
  const int lane = t & 63;
  const int g = lane >> 4;
  const int l16 = lane & 15;
  const int qblk = qt * 256 + w * 64;

  short8 qa[4][2];
#pragma unroll
  for (int sub = 0; sub < 4; ++sub)
#pragma unroll
    for (int c = 0; c < 2; ++c)
      qa[sub][c] = *reinterpret_cast<const short8*>(
          Q + (size_t)(qblk + sub * 16 + l16) * 64 + 32 * c + 8 * g);

  f32x4 oacc[4][4];
#pragma unroll
  for (int sub = 0; sub < 4; ++sub)
#pragma unroll
    for (int db = 0; db < 4; ++db) oacc[sub][db] = f32x4{0.f, 0.f, 0.f, 0.f};
  float l_run[4] = {0.f, 0.f, 0.f, 0.f};

  const int kv0 = (t >> 4) << 2;
  const int d0 = (t & 15) << 2;
  ushort4 kh[4], vh[4];

#define LOADT(tile_)                                                          \
  {                                                                           \
    _Pragma("unroll") for (int j = 0; j < 4; ++j) {                           \
      const size_t off = ((size_t)(kvbase + (tile_)*64 + kv0 + j)) * 64 + d0; \
      kh[j] = *reinterpret_cast<const ushort4*>(K + off);                     \
      vh[j] = *reinterpret_cast<const ushort4*>(V + off);                     \
    }                                                                         \
  }

#define STORET()                                                              \
  {                                                                           \
    _Pragma("unroll") for (int j = 0; j < 4; ++j) {                           \
      const int row = kv0 + j;                                                \
      *reinterpret_cast<ushort4*>(                                            \
          &lds_k[(row * 64 + d0) ^ ((row & 7) << 3)]) = kh[j];                \
    }                                                                         \
    _Pragma("unroll") for (int i = 0; i < 4; ++i) {                           \
      const int row = d0 + i;                                                 \
      ushort4 vt;                                                             \
      vt.x = (&vh[0].x)[i];                                                   \
      vt.y = (&vh[1].x)[i];                                                   \
      vt.z = (&vh[2].x)[i];                                                   \
      vt.w = (&vh[3].x)[i];                                                   \
      *reinterpret_cast<ushort4*>(                                            \
          &lds_vt[(row * 64 + kv0) ^ (((row >> 1) & 7) << 3)]) = vt;          \
    }                                                                         \
  }

  LOADT(0);
  STORET();
  LOADT(1);
  asm volatile("s_waitcnt lgkmcnt(0)" ::: "memory");
  __builtin_amdgcn_s_barrier();
  asm volatile("" ::: "memory");

  for (int tile = 0; tile < 16; ++tile) {
    f32x4 sacc[4][4];
#pragma unroll
    for (int sub = 0; sub < 4; ++sub)
#pragma unroll
      for (int kb = 0; kb < 4; ++kb) sacc[sub][kb] = f32x4{0.f, 0.f, 0.f, 0.f};
#pragma unroll
    for (int c = 0; c < 2; ++c) {
#pragma unroll
      for (int kb = 0; kb < 4; ++kb) {
        const int row = 16 * kb + l16;
        const int idx = (row * 64 + 32 * c + 8 * g) ^ ((row & 7) << 3);
        const short8 kfrag = *reinterpret_cast<const short8*>(&lds_k[idx]);
#pragma unroll
        for (int sub = 0; sub < 4; ++sub)
          sacc[sub][kb] = __builtin_amdgcn_mfma_f32_16x16x32_bf16(
              kfrag, qa[sub][c], sacc[sub][kb], 0, 0, 0);
      }
    }

    short8 pB[4][2];
#pragma unroll
    for (int sub = 0; sub < 4; ++sub) {
      float lsub = 0.f;
#pragma unroll
      for (int kb = 0; kb < 4; ++kb) {
        const float p0 = __expf(sacc[sub][kb][0]);
        const float p1 = __expf(sacc[sub][kb][1]);
        const float p2 = __expf(sacc[sub][kb][2]);
        const float p3 = __expf(sacc[sub][kb][3]);
        lsub += (p0 + p1) + (p2 + p3);
        u32 w0, w1;
        asm("v_cvt_pk_bf16_f32 %0, %1, %2" : "=v"(w0) : "v"(p0), "v"(p1));
        asm("v_cvt_pk_bf16_f32 %0, %1, %2" : "=v"(w1) : "v"(p2), "v"(p3));
        *reinterpret_cast<uint2*>(&lds_p[w][l16 * 34 + 8 * kb + 2 * g]) =
            make_uint2(w0, w1);
      }
      l_run[sub] += lsub;
      asm volatile("" ::: "memory");
#pragma unroll
      for (int c = 0; c < 2; ++c) {
        const int base = l16 * 34 + 16 * c + 4 * g;
        const uint2 a = *reinterpret_cast<const uint2*>(&lds_p[w][base]);
        const uint2 bb = *reinterpret_cast<const uint2*>(&lds_p[w][base + 2]);
        u32 q4[4] = {a.x, a.y, bb.x, bb.y};
        pB[sub][c] = __builtin_bit_cast(short8, *(ulonglong2*)q4);
      }
      asm volatile("" ::: "memory");
    }

#pragma unroll
    for (int c = 0; c < 2; ++c) {
#pragma unroll
      for (int db = 0; db < 4; ++db) {
        const int row = 16 * db + l16;
        const int idx = (row * 64 + 32 * c + 8 * g) ^ (((row >> 1) & 7) << 3);
        const short8 vfrag = *reinterpret_cast<const short8*>(&lds_vt[idx]);
#pragma unroll
        for (int sub = 0; sub < 4; ++sub)
          oacc[sub][db] = __builtin_amdgcn_mfma_f32_16x16x32_bf16(
              vfrag, pB[sub][c], oacc[sub][db], 0, 0, 0);
      }
    }

    asm volatile("s_waitcnt lgkmcnt(0)" ::: "memory");
    __builtin_amdgcn_s_barrier();
    asm volatile("" ::: "memory");
    if (tile < 15) {
      STORET();
      if (tile < 14) LOADT(tile + 2);
    }
    asm volatile("s_waitcnt lgkmcnt(0)" ::: "memory");
    __builtin_amdgcn_s_barrier();
    asm volatile("" ::: "memory");
  }

  const size_t S = (size_t)8192 * 64;
#pragma unroll
  for (int sub = 0; sub < 4; ++sub) {
    const int q = qblk + sub * 16 + l16;
#pragma unroll
    for (int db = 0; db < 4; ++db) {
      u32 w0, w1;
      asm("v_cvt_pk_bf16_f32 %0, %1, %2"
          : "=v"(w0)
          : "v"(oacc[sub][db][0]), "v"(oacc[sub][db][1]));
      asm("v_cvt_pk_bf16_f32 %0, %1, %2"
          : "=v"(w1)
          : "v"(oacc[sub][db][2]), "v"(oacc[sub][db][3]));
      *reinterpret_cast<uint2*>(Opart + (size_t)slab * S + (size_t)q * 64 +
                                16 * db + 4 * g) = make_uint2(w0, w1);
    }
    float lv = l_run[sub];
    lv += __shfl_xor(lv, 16, 64);
    lv += __shfl_xor(lv, 32, 64);
    if (g == 0) lpart[slab * 8192 + q] = lv;
  }
#undef LOADT
#undef STORET
}

// ---------------- post: R16 = R14 body, per-row __syncthreads removed ----------------
// rbuf[4][128] is strictly per-wave. Same-wave LDS write -> cross-lane read
// ordering is the in-wave DS pipe mechanism proven by attn's lds_p (R9-R14)
// and R13's extract; compiler reordering pinned with memory-clobber fences.
// The block-shared weight-staging barrier stays.
__global__ __launch_bounds__(256) void post_kernel(
    const u16* __restrict__ Opart, const float* __restrict__ lpart,
    const float* __restrict__ nirF, const float* __restrict__ libsF,
    const float* __restrict__ ln1g, const float* __restrict__ ln1b,
    const float* __restrict__ fc1w, const float* __restrict__ fc1b,
    const float* __restrict__ ln2g, const float* __restrict__ ln2b,
    const float* __restrict__ fc2w, const float* __restrict__ fc2b,
    const float* __restrict__ ln0g, const float* __restrict__ ln0b,
    const float* __restrict__ gatew, const float* __restrict__ gateb,
    const float* __restrict__ ln3g, const float* __restrict__ ln3b,
    const float* __restrict__ fc3w, const float* __restrict__ fc3b,
    const float* __restrict__ ln4g, const float* __restrict__ ln4b,
    const float* __restrict__ fc4w, const float* __restrict__ fc4b,
    float* __restrict__ out) {
  __shared__ u16 FC1[4096], FC2[4096], FC3[2048];
  __shared__ u16 GW[8192];
  __shared__ float rbuf[4][128];
  const int t = threadIdx.x, w = t >> 6, lane = t & 63;
  const size_t S = (size_t)8192 * 64;
  for (int i = t; i < 4096; i += 256) {
    FC1[i] = f2bf(fc1w[i]);
    FC2[i] = f2bf(fc2w[i]);
  }
  for (int i = t; i < 2048; i += 256) FC3[i] = f2bf(fc3w[i]);
  for (int i = t; i < 8192; i += 256) GW[i] = f2bf(gatew[i]);
  __syncthreads();  // block-shared weight staging: barrier required
#pragma unroll
  for (int rr = 0; rr < 2; ++rr) {
    const int r = blockIdx.x * 8 + rr * 4 + w;
    const size_t ro = (size_t)r * 64;

    // merge 8 KV-splits per direction (no-max: plain sums), bf16 partials
    float a1 = 0.f, a2 = 0.f, l1 = 0.f, l2 = 0.f;
#pragma unroll
    for (int s = 0; s < 8; ++s) {
      a1 += bf2f(Opart[(size_t)s * S + ro + lane]);
      a2 += bf2f(Opart[(size_t)(8 + s) * S + ro + lane]);
      l1 += lpart[s * 8192 + r];
      l2 += lpart[(8 + s) * 8192 + r];
    }
    a1 /= l1;  // attn_libs_to_nir
    a2 /= l2;  // attn_nir_to_libs

    const float nv = nirF[ro + lane], lv_ = libsF[ro + lane];

    // out1 = relu(LN(a2; ln1) @ fc1 + b) + libs   (rbuf per-wave: fence only)
    float s1 = wave_sum64(a2), ss1 = wave_sum64(a2 * a2);
    float mean = s1 * (1.f / 64);
    float rstd = rsqrtf(ss1 * (1.f / 64) - mean * mean + LN_EPS);
    rbuf[w][lane] = (a2 - mean) * rstd * ln1g[lane] + ln1b[lane];
    asm volatile("" ::: "memory");
    float o1 = fc1b[lane];
#pragma unroll 8
    for (int i = 0; i < 64; ++i)
      o1 = fmaf(rbuf[w][i], bf2f(FC1[i * 64 + lane]), o1);
    const float out1 = fmaxf(o1, 0.f) + lv_;
    asm volatile("" ::: "memory");

    // out2 = relu(LN(a1; ln2) @ fc2 + b) + nir
    s1 = wave_sum64(a1);
    ss1 = wave_sum64(a1 * a1);
    mean = s1 * (1.f / 64);
    rstd = rsqrtf(ss1 * (1.f / 64) - mean * mean + LN_EPS);
    rbuf[w][lane] = (a1 - mean) * rstd * ln2g[lane] + ln2b[lane];
    asm volatile("" ::: "memory");
    float o2 = fc2b[lane];
#pragma unroll 8
    for (int i = 0; i < 64; ++i)
      o2 = fmaf(rbuf[w][i], bf2f(FC2[i * 64 + lane]), o2);
    const float out2 = fmaxf(o2, 0.f) + nv;
    asm volatile("" ::: "memory");

    // gate
    s1 = wave_sum64(out1 + out2);
    ss1 = wave_sum64(out1 * out1 + out2 * out2);
    mean = s1 * (1.f / 128);
    rstd = rsqrtf(ss1 * (1.f / 128) - mean * mean + LN_EPS);
    rbuf[w][lane] = (out1 - mean) * rstd * ln0g[lane] + ln0b[lane];
    rbuf[w][64 + lane] =
        (out2 - mean) * rstd * ln0g[64 + lane] + ln0b[64 + lane];
    asm volatile("" ::: "memory");
    float gg = gateb[lane];
#pragma unroll 8
    for (int i = 0; i < 128; ++i)
      gg = fmaf(rbuf[w][i], bf2f(GW[i * 64 + lane]), gg);
    gg = 1.f / (1.f + __expf(-gg));
    const float fused = gg * out1 + (1.f - gg) * out2;
    asm volatile("" ::: "memory");

    // head: LN -> fc3 -> relu -> LN -> fc4
    s1 = wave_sum64(fused);
    ss1 = wave_sum64(fused * fused);
    mean = s1 * (1.f / 64);
    rstd = rsqrtf(ss1 * (1.f / 64) - mean * mean + LN_EPS);
    rbuf[w][lane] = (fused - mean) * rstd * ln3g[lane] + ln3b[lane];
    asm volatile("" ::: "memory");
    if (lane < 32) {
      float h = fc3b[lane];
#pragma unroll 8
      for (int i = 0; i < 64; ++i)
        h = fmaf(rbuf[w][i], bf2f(FC3[i * 32 + lane]), h);
      h = fmaxf(h, 0.f);
      const float hs = grp32_sum(h), hss = grp32_sum(h * h);
      const float hm = hs * (1.f / 32);
      const float hr = rsqrtf(hss * (1.f / 32) - hm * hm + LN_EPS);
      const float y4 = (h - hm) * hr * ln4g[lane] + ln4b[lane];
      const float part = grp32_sum(y4 * fc4w[lane]);
      if (lane == 0) out[r] = part + fc4b[0];
    }
    asm volatile("" ::: "memory");
  }
}

extern "C" void kernel_launch(void* const* d_in, const int* in_sizes, int n_in,
                              void* d_out, int out_size, void* d_ws,
                              size_t ws_size, hipStream_t stream) {
  const float* nir_data = (const float*)d_in[0];
  const float* libs_data = (const float*)d_in[1];
  const float* nir_ln_g = (const float*)d_in[2];
  const float* nir_ln_b = (const float*)d_in[3];
  const float* nir_w = (const float*)d_in[4];
  const float* nir_b = (const float*)d_in[5];
  const float* libs_ln_g = (const float*)d_in[6];
  const float* libs_ln_b = (const float*)d_in[7];
  const float* libs_w = (const float*)d_in[8];
  const float* libs_b = (const float*)d_in[9];
  const float* q_ln_w = (const float*)d_in[10];
  const float* q_ln_b = (const float*)d_in[11];
  const float* k_ln_w = (const float*)d_in[12];
  const float* k_ln_b = (const float*)d_in[13];
  const float* v_ln_w = (const float*)d_in[14];
  const float* v_ln_b = (const float*)d_in[15];
  const float* q_nl_w = (const float*)d_in[16];
  const float* q_nl_b = (const float*)d_in[17];
  const float* k_nl_w = (const float*)d_in[18];
  const float* k_nl_b = (const float*)d_in[19];
  const float* v_nl_w = (const float*)d_in[20];
  const float* v_nl_b = (const float*)d_in[21];
  const float* ln1_g = (const float*)d_in[22];
  const float* ln1_b = (const float*)d_in[23];
  const float* fc1_w = (const float*)d_in[24];
  const float* fc1_b = (const float*)d_in[25];
  const float* ln2_g = (const float*)d_in[26];
  const float* ln2_b = (const float*)d_in[27];
  const float* fc2_w = (const float*)d_in[28];
  const float* fc2_b = (const float*)d_in[29];
  const float* ln0_g = (const float*)d_in[30];
  const float* ln0_b = (const float*)d_in[31];
  const float* gate_w = (const float*)d_in[32];
  const float* gate_b = (const float*)d_in[33];
  const float* ln3_g = (const float*)d_in[34];
  const float* ln3_b = (const float*)d_in[35];
  const float* fc3_w = (const float*)d_in[36];
  const float* fc3_b = (const float*)d_in[37];
  const float* ln4_g = (const float*)d_in[38];
  const float* ln4_b = (const float*)d_in[39];
  const float* fc4_w = (const float*)d_in[40];
  const float* fc4_b = (const float*)d_in[41];

  const size_t S = (size_t)8192 * 64;
  u16* ub = (u16*)d_ws;
  u16* Qb_nir = ub + 0 * S;
  u16* Kb_nir = ub + 1 * S;
  u16* Vb_nir = ub + 2 * S;
  u16* Qb_libs = ub + 3 * S;
  u16* Kb_libs = ub + 4 * S;
  u16* Vb_libs = ub + 5 * S;
  u16* OpartU = ub + 6 * S;  // 16 slabs bf16 (2 dirs x 8 splits)
  float* fp = (float*)(ub + 22 * S);
  float* f_nir = fp + 0 * S;
  float* f_libs = fp + 1 * S;
  float* lpart = fp + 2 * S;  // 16 x 8192

  extract_fused_kernel<<<512, 256, 0, stream>>>(
      nir_data, libs_data, nir_ln_g, nir_ln_b, nir_w, nir_b, libs_ln_g,
      libs_ln_b, libs_w, libs_b, q_ln_w, q_ln_b, k_ln_w, k_ln_b, v_ln_w,
      v_ln_b, q_nl_w, q_nl_b, k_nl_w, k_nl_b, v_nl_w, v_nl_b, f_nir, f_libs,
      Qb_nir, Kb_nir, Vb_nir, Qb_libs, Kb_libs, Vb_libs);

  // dir0: Q_libs x K/V_nir ; dir1: Q_nir x K/V_libs
  attn_mfma_kernel<<<512, 256, 0, stream>>>(Qb_libs, Kb_nir, Vb_nir, Qb_nir,
                                            Kb_libs, Vb_libs, OpartU, lpart);

  post_kernel<<<1024, 256, 0, stream>>>(
      OpartU, lpart, f_nir, f_libs, ln1_g, ln1_b, fc1_w, fc1_b, ln2_g, ln2_b,
      fc2_w, fc2_b, ln0_g, ln0_b, gate_w, gate_b, ln3_g, ln3_b, fc3_w, fc3_b,
      ln4_g, ln4_b, fc4_w, fc4_b, (float*)d_out);
}

// Round 18
// 93.208 us; speedup vs baseline: 1.4102x; 1.0021x over previous
//
#include <hip/hip_runtime.h>
#include <hip/hip_bf16.h>
#include <math.h>

#define LN_EPS 1e-5f

typedef __attribute__((ext_vector_type(8))) short short8;
typedef __attribute__((ext_vector_type(4))) float f32x4;
typedef unsigned short u16;
typedef unsigned int u32;

__device__ __forceinline__ u16 f2bf(float f) {
  __hip_bfloat16 h = __float2bfloat16(f);
  return __builtin_bit_cast(u16, h);
}
__device__ __forceinline__ float bf2f(u16 u) {
  u32 x = ((u32)u) << 16;
  return __builtin_bit_cast(float, x);
}

// ---------------- wave reduction helpers ----------------
__device__ __forceinline__ float wave_sum64(float v) {
#pragma unroll
  for (int m = 1; m <= 32; m <<= 1) v += __shfl_xor(v, m, 64);
  return v;
}
__device__ __forceinline__ float grp32_sum(float v) {
#pragma unroll
  for (int m = 1; m <= 16; m <<= 1) v += __shfl_xor(v, m, 64);
  return v;
}

// ---------------- extractor, MFMA version (R14-proven, byte-identical) ----------------
template <int DM, int KSTEPS>
__device__ __forceinline__ void extract_mfma_body(
    int rbase, u16* xt, u16* ft, const float* __restrict__ xin,
    const float* __restrict__ lng, const float* __restrict__ lnb,
    const float* __restrict__ We, const float* __restrict__ be,
    const float* __restrict__ Wq, const float* __restrict__ bq,
    const float* __restrict__ Wk, const float* __restrict__ bk,
    const float* __restrict__ Wv, const float* __restrict__ bv,
    float* __restrict__ featOut, u16* __restrict__ Qout,
    u16* __restrict__ Kout, u16* __restrict__ Vout) {
  const int t = threadIdx.x, w = t >> 6, lane = t & 63;
  const int g = lane >> 4, l16 = lane & 15;
  const int c = 16 * w + l16;  // A-frag row = this lane's weight column

  // ---- A-fragments: gather f32 weights -> bf16 regs (issued early) ----
  short8 wf[KSTEPS];
#pragma unroll
  for (int kc = 0; kc < KSTEPS; ++kc) {
    short8 f;
#pragma unroll
    for (int i = 0; i < 8; ++i) {
      const int k = kc * 32 + 8 * g + i;
      f[i] = (short)((k < DM) ? f2bf(We[(size_t)k * 64 + c]) : (u16)0);
    }
    wf[kc] = f;
  }
  short8 qf[2], kf[2], vf[2];
#pragma unroll
  for (int kc = 0; kc < 2; ++kc) {
    short8 fq, fk, fv;
#pragma unroll
    for (int i = 0; i < 8; ++i) {
      const int k = kc * 32 + 8 * g + i;
      fq[i] = (short)f2bf(Wq[k * 64 + c]);
      fk[i] = (short)f2bf(Wk[k * 64 + c]);
      fv[i] = (short)f2bf(Wv[k * 64 + c]);
    }
    qf[kc] = fq;
    kf[kc] = fk;
    vf[kc] = fv;
  }

  // ---- LN: 8 rows/wave (4 passes x 2-row ILP), bf16 swizzled xt ----
#pragma unroll
  for (int pp = 0; pp < 4; ++pp) {
    const int lrA = 8 * w + pp * 2;
    const int lrB = lrA + 1;
    const float* xA = xin + (size_t)(rbase + lrA) * DM;
    const float* xB = xin + (size_t)(rbase + lrB) * DM;
    float xrA[4], xrB[4];
    float sA = 0.f, ssA = 0.f, sB = 0.f, ssB = 0.f;
#pragma unroll
    for (int u = 0; u < 4; ++u) {
      const int idx = u * 64 + lane;
      const float vA = (idx < DM) ? xA[idx] : 0.f;
      const float vB = (idx < DM) ? xB[idx] : 0.f;
      xrA[u] = vA;
      xrB[u] = vB;
      sA += vA;
      ssA += vA * vA;
      sB += vB;
      ssB += vB * vB;
    }
    sA = wave_sum64(sA);
    ssA = wave_sum64(ssA);
    sB = wave_sum64(sB);
    ssB = wave_sum64(ssB);
    const float mA = sA / (float)DM;
    const float rAs = rsqrtf(ssA / (float)DM - mA * mA + LN_EPS);
    const float mB = sB / (float)DM;
    const float rBs = rsqrtf(ssB / (float)DM - mB * mB + LN_EPS);
#pragma unroll
    for (int u = 0; u < 4; ++u) {
      const int idx = u * 64 + lane;
      float yA = 0.f, yB = 0.f;
      if (idx < DM) {
        const float gg = lng[idx], bb = lnb[idx];
        yA = (xrA[u] - mA) * rAs * gg + bb;
        yB = (xrB[u] - mB) * rBs * gg + bb;
      }
      xt[(lrA * 256 + idx) ^ ((lrA & 7) << 3)] = f2bf(yA);
      xt[(lrB * 256 + idx) ^ ((lrB & 7) << 3)] = f2bf(yB);
    }
  }
  __syncthreads();

  // ---- Feat = LN(x) @ We + be, ReLU -> f32 featOut + bf16 ft ----
  const float4 bev = *reinterpret_cast<const float4*>(&be[16 * w + 4 * g]);
#pragma unroll
  for (int sub = 0; sub < 2; ++sub) {
    const int lr = sub * 16 + l16;
    f32x4 acc = f32x4{0.f, 0.f, 0.f, 0.f};
#pragma unroll
    for (int kc = 0; kc < KSTEPS; ++kc) {
      const short8 xf = *reinterpret_cast<const short8*>(
          &xt[(lr * 256 + kc * 32 + 8 * g) ^ ((lr & 7) << 3)]);
      acc = __builtin_amdgcn_mfma_f32_16x16x32_bf16(wf[kc], xf, acc, 0, 0, 0);
    }
    const float f0 = fmaxf(acc[0] + bev.x, 0.f);
    const float f1 = fmaxf(acc[1] + bev.y, 0.f);
    const float f2 = fmaxf(acc[2] + bev.z, 0.f);
    const float f3 = fmaxf(acc[3] + bev.w, 0.f);
    *reinterpret_cast<float4*>(
        &featOut[(size_t)(rbase + lr) * 64 + 16 * w + 4 * g]) =
        make_float4(f0, f1, f2, f3);
    u32 p0, p1;
    asm("v_cvt_pk_bf16_f32 %0, %1, %2" : "=v"(p0) : "v"(f0), "v"(f1));
    asm("v_cvt_pk_bf16_f32 %0, %1, %2" : "=v"(p1) : "v"(f2), "v"(f3));
    *reinterpret_cast<uint2*>(&ft[(lr * 64 + 16 * w + 4 * g) ^
                                  ((lr & 7) << 3)]) = make_uint2(p0, p1);
  }
  __syncthreads();

  // ---- Q/K/V = Feat @ W* + b* (Q scaled by 1/8) ----
  const float4 bqv = *reinterpret_cast<const float4*>(&bq[16 * w + 4 * g]);
  const float4 bkv = *reinterpret_cast<const float4*>(&bk[16 * w + 4 * g]);
  const float4 bvv = *reinterpret_cast<const float4*>(&bv[16 * w + 4 * g]);
#pragma unroll
  for (int sub = 0; sub < 2; ++sub) {
    const int lr = sub * 16 + l16;
    const short8 xf0 = *reinterpret_cast<const short8*>(
        &ft[(lr * 64 + 0 * 32 + 8 * g) ^ ((lr & 7) << 3)]);
    const short8 xf1 = *reinterpret_cast<const short8*>(
        &ft[(lr * 64 + 1 * 32 + 8 * g) ^ ((lr & 7) << 3)]);
    f32x4 aq = f32x4{0.f, 0.f, 0.f, 0.f};
    f32x4 ak = f32x4{0.f, 0.f, 0.f, 0.f};
    f32x4 av = f32x4{0.f, 0.f, 0.f, 0.f};
    aq = __builtin_amdgcn_mfma_f32_16x16x32_bf16(qf[0], xf0, aq, 0, 0, 0);
    aq = __builtin_amdgcn_mfma_f32_16x16x32_bf16(qf[1], xf1, aq, 0, 0, 0);
    ak = __builtin_amdgcn_mfma_f32_16x16x32_bf16(kf[0], xf0, ak, 0, 0, 0);
    ak = __builtin_amdgcn_mfma_f32_16x16x32_bf16(kf[1], xf1, ak, 0, 0, 0);
    av = __builtin_amdgcn_mfma_f32_16x16x32_bf16(vf[0], xf0, av, 0, 0, 0);
    av = __builtin_amdgcn_mfma_f32_16x16x32_bf16(vf[1], xf1, av, 0, 0, 0);
    const size_t off = (size_t)(rbase + lr) * 64 + 16 * w + 4 * g;
    u32 a0, a1;
    asm("v_cvt_pk_bf16_f32 %0, %1, %2"
        : "=v"(a0)
        : "v"((aq[0] + bqv.x) * 0.125f), "v"((aq[1] + bqv.y) * 0.125f));
    asm("v_cvt_pk_bf16_f32 %0, %1, %2"
        : "=v"(a1)
        : "v"((aq[2] + bqv.z) * 0.125f), "v"((aq[3] + bqv.w) * 0.125f));
    *reinterpret_cast<uint2*>(Qout + off) = make_uint2(a0, a1);
    asm("v_cvt_pk_bf16_f32 %0, %1, %2"
        : "=v"(a0)
        : "v"(ak[0] + bkv.x), "v"(ak[1] + bkv.y));
    asm("v_cvt_pk_bf16_f32 %0, %1, %2"
        : "=v"(a1)
        : "v"(ak[2] + bkv.z), "v"(ak[3] + bkv.w));
    *reinterpret_cast<uint2*>(Kout + off) = make_uint2(a0, a1);
    asm("v_cvt_pk_bf16_f32 %0, %1, %2"
        : "=v"(a0)
        : "v"(av[0] + bvv.x), "v"(av[1] + bvv.y));
    asm("v_cvt_pk_bf16_f32 %0, %1, %2"
        : "=v"(a1)
        : "v"(av[2] + bvv.z), "v"(av[3] + bvv.w));
    *reinterpret_cast<uint2*>(Vout + off) = make_uint2(a0, a1);
  }
}

// blocks [0,256) nir, [256,512) libs; 32 rows/block
__global__ __launch_bounds__(256) void extract_fused_kernel(
    const float* __restrict__ nir_x, const float* __restrict__ libs_x,
    const float* __restrict__ n_lng, const float* __restrict__ n_lnb,
    const float* __restrict__ n_We, const float* __restrict__ n_be,
    const float* __restrict__ l_lng, const float* __restrict__ l_lnb,
    const float* __restrict__ l_We, const float* __restrict__ l_be,
    const float* __restrict__ q_ln_w, const float* __restrict__ q_ln_b,
    const float* __restrict__ k_ln_w, const float* __restrict__ k_ln_b,
    const float* __restrict__ v_ln_w, const float* __restrict__ v_ln_b,
    const float* __restrict__ q_nl_w, const float* __restrict__ q_nl_b,
    const float* __restrict__ k_nl_w, const float* __restrict__ k_nl_b,
    const float* __restrict__ v_nl_w, const float* __restrict__ v_nl_b,
    float* __restrict__ f_nir, float* __restrict__ f_libs,
    u16* __restrict__ Qb_nir, u16* __restrict__ Kb_nir,
    u16* __restrict__ Vb_nir, u16* __restrict__ Qb_libs,
    u16* __restrict__ Kb_libs, u16* __restrict__ Vb_libs) {
  __shared__ __align__(16) u16 xt[32 * 256];
  __shared__ __align__(16) u16 ft[32 * 64];
  if (blockIdx.x < 256) {
    extract_mfma_body<215, 7>(blockIdx.x * 32, xt, ft, nir_x, n_lng, n_lnb,
                              n_We, n_be, q_nl_w, q_nl_b, k_ln_w, k_ln_b,
                              v_ln_w, v_ln_b, f_nir, Qb_nir, Kb_nir, Vb_nir);
  } else {
    extract_mfma_body<244, 8>((blockIdx.x - 256) * 32, xt, ft, libs_x, l_lng,
                              l_lnb, l_We, l_be, q_ln_w, q_ln_b, k_nl_w,
                              k_nl_b, v_nl_w, v_nl_b, f_libs, Qb_libs,
                              Kb_libs, Vb_libs);
  }
}

// ---------------- flash attention (R14-proven, byte-identical) ----------------
__global__ __launch_bounds__(256, 2) void attn_mfma_kernel(
    const u16* __restrict__ Qb0, const u16* __restrict__ Kb0,
    const u16* __restrict__ Vb0, const u16* __restrict__ Qb1,
    const u16* __restrict__ Kb1, const u16* __restrict__ Vb1,
    u16* __restrict__ Opart, float* __restrict__ lpart) {
  __shared__ __align__(16) u16 lds_k[4096];    // [kv][d] ^ ((kv&7)<<3)
  __shared__ __align__(16) u16 lds_vt[4096];   // [d][kv] ^ (((d>>1)&7)<<3)
  __shared__ __align__(16) u32 lds_p[4][544];  // per-wave [16 q][34], reused per sub

  const int bid = blockIdx.x;
  const int split = bid & 7;
  const int dir = (bid >> 3) & 1;
  const int qt = bid >> 4;
  const int slab = dir * 8 + split;
  const int kvbase = split * 1024;

  const u16* Q = dir ? Qb1 : Qb0;
  const u16* K = dir ? Kb1 : Kb0;
  const u16* V = dir ? Vb1 : Vb0;

  const int t = threadIdx.x;
  const int w = t >> 6;
  const int lane = t & 63;
  const int g = lane >> 4;
  const int l16 = lane & 15;
  const int qblk = qt * 256 + w * 64;

  short8 qa[4][2];
#pragma unroll
  for (int sub = 0; sub < 4; ++sub)
#pragma unroll
    for (int c = 0; c < 2; ++c)
      qa[sub][c] = *reinterpret_cast<const short8*>(
          Q + (size_t)(qblk + sub * 16 + l16) * 64 + 32 * c + 8 * g);

  f32x4 oacc[4][4];
#pragma unroll
  for (int sub = 0; sub < 4; ++sub)
#pragma unroll
    for (int db = 0; db < 4; ++db) oacc[sub][db] = f32x4{0.f, 0.f, 0.f, 0.f};
  float l_run[4] = {0.f, 0.f, 0.f, 0.f};

  const int kv0 = (t >> 4) << 2;
  const int d0 = (t & 15) << 2;
  ushort4 kh[4], vh[4];

#define LOADT(tile_)                                                          \
  {                                                                           \
    _Pragma("unroll") for (int j = 0; j < 4; ++j) {                           \
      const size_t off = ((size_t)(kvbase + (tile_)*64 + kv0 + j)) * 64 + d0; \
      kh[j] = *reinterpret_cast<const ushort4*>(K + off);                     \
      vh[j] = *reinterpret_cast<const ushort4*>(V + off);                     \
    }                                                                         \
  }

#define STORET()                                                              \
  {                                                                           \
    _Pragma("unroll") for (int j = 0; j < 4; ++j) {                           \
      const int row = kv0 + j;                                                \
      *reinterpret_cast<ushort4*>(                                            \
          &lds_k[(row * 64 + d0) ^ ((row & 7) << 3)]) = kh[j];                \
    }                                                                         \
    _Pragma("unroll") for (int i = 0; i < 4; ++i) {                           \
      const int row = d0 + i;                                                 \
      ushort4 vt;                                                             \
      vt.x = (&vh[0].x)[i];                                                   \
      vt.y = (&vh[1].x)[i];                                                   \
      vt.z = (&vh[2].x)[i];                                                   \
      vt.w = (&vh[3].x)[i];                                                   \
      *reinterpret_cast<ushort4*>(                                            \
          &lds_vt[(row * 64 + kv0) ^ (((row >> 1) & 7) << 3)]) = vt;          \
    }                                                                         \
  }

  LOADT(0);
  STORET();
  LOADT(1);
  asm volatile("s_waitcnt lgkmcnt(0)" ::: "memory");
  __builtin_amdgcn_s_barrier();
  asm volatile("" ::: "memory");

  for (int tile = 0; tile < 16; ++tile) {
    f32x4 sacc[4][4];
#pragma unroll
    for (int sub = 0; sub < 4; ++sub)
#pragma unroll
      for (int kb = 0; kb < 4; ++kb) sacc[sub][kb] = f32x4{0.f, 0.f, 0.f, 0.f};
#pragma unroll
    for (int c = 0; c < 2; ++c) {
#pragma unroll
      for (int kb = 0; kb < 4; ++kb) {
        const int row = 16 * kb + l16;
        const int idx = (row * 64 + 32 * c + 8 * g) ^ ((row & 7) << 3);
        const short8 kfrag = *reinterpret_cast<const short8*>(&lds_k[idx]);
#pragma unroll
        for (int sub = 0; sub < 4; ++sub)
          sacc[sub][kb] = __builtin_amdgcn_mfma_f32_16x16x32_bf16(
              kfrag, qa[sub][c], sacc[sub][kb], 0, 0, 0);
      }
    }

    short8 pB[4][2];
#pragma unroll
    for (int sub = 0; sub < 4; ++sub) {
      float lsub = 0.f;
#pragma unroll
      for (int kb = 0; kb < 4; ++kb) {
        const float p0 = __expf(sacc[sub][kb][0]);
        const float p1 = __expf(sacc[sub][kb][1]);
        const float p2 = __expf(sacc[sub][kb][2]);
        const float p3 = __expf(sacc[sub][kb][3]);
        lsub += (p0 + p1) + (p2 + p3);
        u32 w0, w1;
        asm("v_cvt_pk_bf16_f32 %0, %1, %2" : "=v"(w0) : "v"(p0), "v"(p1));
        asm("v_cvt_pk_bf16_f32 %0, %1, %2" : "=v"(w1) : "v"(p2), "v"(p3));
        *reinterpret_cast<uint2*>(&lds_p[w][l16 * 34 + 8 * kb + 2 * g]) =
            make_uint2(w0, w1);
      }
      l_run[sub] += lsub;
      asm volatile("" ::: "memory");
#pragma unroll
      for (int c = 0; c < 2; ++c) {
        const int base = l16 * 34 + 16 * c + 4 * g;
        const uint2 a = *reinterpret_cast<const uint2*>(&lds_p[w][base]);
        const uint2 bb = *reinterpret_cast<const uint2*>(&lds_p[w][base + 2]);
        u32 q4[4] = {a.x, a.y, bb.x, bb.y};
        pB[sub][c] = __builtin_bit_cast(short8, *(ulonglong2*)q4);
      }
      asm volatile("" ::: "memory");
    }

#pragma unroll
    for (int c = 0; c < 2; ++c) {
#pragma unroll
      for (int db = 0; db < 4; ++db) {
        const int row = 16 * db + l16;
        const int idx = (row * 64 + 32 * c + 8 * g) ^ (((row >> 1) & 7) << 3);
        const short8 vfrag = *reinterpret_cast<const short8*>(&lds_vt[idx]);
#pragma unroll
        for (int sub = 0; sub < 4; ++sub)
          oacc[sub][db] = __builtin_amdgcn_mfma_f32_16x16x32_bf16(
              vfrag, pB[sub][c], oacc[sub][db], 0, 0, 0);
      }
    }

    asm volatile("s_waitcnt lgkmcnt(0)" ::: "memory");
    __builtin_amdgcn_s_barrier();
    asm volatile("" ::: "memory");
    if (tile < 15) {
      STORET();
      if (tile < 14) LOADT(tile + 2);
    }
    asm volatile("s_waitcnt lgkmcnt(0)" ::: "memory");
    __builtin_amdgcn_s_barrier();
    asm volatile("" ::: "memory");
  }

  const size_t S = (size_t)8192 * 64;
#pragma unroll
  for (int sub = 0; sub < 4; ++sub) {
    const int q = qblk + sub * 16 + l16;
#pragma unroll
    for (int db = 0; db < 4; ++db) {
      u32 w0, w1;
      asm("v_cvt_pk_bf16_f32 %0, %1, %2"
          : "=v"(w0)
          : "v"(oacc[sub][db][0]), "v"(oacc[sub][db][1]));
      asm("v_cvt_pk_bf16_f32 %0, %1, %2"
          : "=v"(w1)
          : "v"(oacc[sub][db][2]), "v"(oacc[sub][db][3]));
      *reinterpret_cast<uint2*>(Opart + (size_t)slab * S + (size_t)q * 64 +
                                16 * db + 4 * g) = make_uint2(w0, w1);
    }
    float lv = l_run[sub];
    lv += __shfl_xor(lv, 16, 64);
    lv += __shfl_xor(lv, 32, 64);
    if (g == 0) lpart[slab * 8192 + q] = lv;
  }
#undef LOADT
#undef STORET
}

// ---------------- post (R16-proven, byte-identical) ----------------
__global__ __launch_bounds__(256) void post_kernel(
    const u16* __restrict__ Opart, const float* __restrict__ lpart,
    const float* __restrict__ nirF, const float* __restrict__ libsF,
    const float* __restrict__ ln1g, const float* __restrict__ ln1b,
    const float* __restrict__ fc1w, const float* __restrict__ fc1b,
    const float* __restrict__ ln2g, const float* __restrict__ ln2b,
    const float* __restrict__ fc2w, const float* __restrict__ fc2b,
    const float* __restrict__ ln0g, const float* __restrict__ ln0b,
    const float* __restrict__ gatew, const float* __restrict__ gateb,
    const float* __restrict__ ln3g, const float* __restrict__ ln3b,
    const float* __restrict__ fc3w, const float* __restrict__ fc3b,
    const float* __restrict__ ln4g, const float* __restrict__ ln4b,
    const float* __restrict__ fc4w, const float* __restrict__ fc4b,
    float* __restrict__ out) {
  __shared__ u16 FC1[4096], FC2[4096], FC3[2048];
  __shared__ u16 GW[8192];
  __shared__ float rbuf[4][128];
  const int t = threadIdx.x, w = t >> 6, lane = t & 63;
  const size_t S = (size_t)8192 * 64;
  for (int i = t; i < 4096; i += 256) {
    FC1[i] = f2bf(fc1w[i]);
    FC2[i] = f2bf(fc2w[i]);
  }
  for (int i = t; i < 2048; i += 256) FC3[i] = f2bf(fc3w[i]);
  for (int i = t; i < 8192; i += 256) GW[i] = f2bf(gatew[i]);
  __syncthreads();  // block-shared weight staging: barrier required
#pragma unroll
  for (int rr = 0; rr < 2; ++rr) {
    const int r = blockIdx.x * 8 + rr * 4 + w;
    const size_t ro = (size_t)r * 64;

    float a1 = 0.f, a2 = 0.f, l1 = 0.f, l2 = 0.f;
#pragma unroll
    for (int s = 0; s < 8; ++s) {
      a1 += bf2f(Opart[(size_t)s * S + ro + lane]);
      a2 += bf2f(Opart[(size_t)(8 + s) * S + ro + lane]);
      l1 += lpart[s * 8192 + r];
      l2 += lpart[(8 + s) * 8192 + r];
    }
    a1 /= l1;  // attn_libs_to_nir
    a2 /= l2;  // attn_nir_to_libs

    const float nv = nirF[ro + lane], lv_ = libsF[ro + lane];

    float s1 = wave_sum64(a2), ss1 = wave_sum64(a2 * a2);
    float mean = s1 * (1.f / 64);
    float rstd = rsqrtf(ss1 * (1.f / 64) - mean * mean + LN_EPS);
    rbuf[w][lane] = (a2 - mean) * rstd * ln1g[lane] + ln1b[lane];
    asm volatile("" ::: "memory");
    float o1 = fc1b[lane];
#pragma unroll 8
    for (int i = 0; i < 64; ++i)
      o1 = fmaf(rbuf[w][i], bf2f(FC1[i * 64 + lane]), o1);
    const float out1 = fmaxf(o1, 0.f) + lv_;
    asm volatile("" ::: "memory");

    s1 = wave_sum64(a1);
    ss1 = wave_sum64(a1 * a1);
    mean = s1 * (1.f / 64);
    rstd = rsqrtf(ss1 * (1.f / 64) - mean * mean + LN_EPS);
    rbuf[w][lane] = (a1 - mean) * rstd * ln2g[lane] + ln2b[lane];
    asm volatile("" ::: "memory");
    float o2 = fc2b[lane];
#pragma unroll 8
    for (int i = 0; i < 64; ++i)
      o2 = fmaf(rbuf[w][i], bf2f(FC2[i * 64 + lane]), o2);
    const float out2 = fmaxf(o2, 0.f) + nv;
    asm volatile("" ::: "memory");

    s1 = wave_sum64(out1 + out2);
    ss1 = wave_sum64(out1 * out1 + out2 * out2);
    mean = s1 * (1.f / 128);
    rstd = rsqrtf(ss1 * (1.f / 128) - mean * mean + LN_EPS);
    rbuf[w][lane] = (out1 - mean) * rstd * ln0g[lane] + ln0b[lane];
    rbuf[w][64 + lane] =
        (out2 - mean) * rstd * ln0g[64 + lane] + ln0b[64 + lane];
    asm volatile("" ::: "memory");
    float gg = gateb[lane];
#pragma unroll 8
    for (int i = 0; i < 128; ++i)
      gg = fmaf(rbuf[w][i], bf2f(GW[i * 64 + lane]), gg);
    gg = 1.f / (1.f + __expf(-gg));
    const float fused = gg * out1 + (1.f - gg) * out2;
    asm volatile("" ::: "memory");

    s1 = wave_sum64(fused);
    ss1 = wave_sum64(fused * fused);
    mean = s1 * (1.f / 64);
    rstd = rsqrtf(ss1 * (1.f / 64) - mean * mean + LN_EPS);
    rbuf[w][lane] = (fused - mean) * rstd * ln3g[lane] + ln3b[lane];
    asm volatile("" ::: "memory");
    if (lane < 32) {
      float h = fc3b[lane];
#pragma unroll 8
      for (int i = 0; i < 64; ++i)
        h = fmaf(rbuf[w][i], bf2f(FC3[i * 32 + lane]), h);
      h = fmaxf(h, 0.f);
      const float hs = grp32_sum(h), hss = grp32_sum(h * h);
      const float hm = hs * (1.f / 32);
      const float hr = rsqrtf(hss * (1.f / 32) - hm * hm + LN_EPS);
      const float y4 = (h - hm) * hr * ln4g[lane] + ln4b[lane];
      const float part = grp32_sum(y4 * fc4w[lane]);
      if (lane == 0) out[r] = part + fc4b[0];
    }
    asm volatile("" ::: "memory");
  }
}

extern "C" void kernel_launch(void* const* d_in, const int* in_sizes, int n_in,
                              void* d_out, int out_size, void* d_ws,
                              size_t ws_size, hipStream_t stream) {
  const float* nir_data = (const float*)d_in[0];
  const float* libs_data = (const float*)d_in[1];
  const float* nir_ln_g = (const float*)d_in[2];
  const float* nir_ln_b = (const float*)d_in[3];
  const float* nir_w = (const float*)d_in[4];
  const float* nir_b = (const float*)d_in[5];
  const float* libs_ln_g = (const float*)d_in[6];
  const float* libs_ln_b = (const float*)d_in[7];
  const float* libs_w = (const float*)d_in[8];
  const float* libs_b = (const float*)d_in[9];
  const float* q_ln_w = (const float*)d_in[10];
  const float* q_ln_b = (const float*)d_in[11];
  const float* k_ln_w = (const float*)d_in[12];
  const float* k_ln_b = (const float*)d_in[13];
  const float* v_ln_w = (const float*)d_in[14];
  const float* v_ln_b = (const float*)d_in[15];
  const float* q_nl_w = (const float*)d_in[16];
  const float* q_nl_b = (const float*)d_in[17];
  const float* k_nl_w = (const float*)d_in[18];
  const float* k_nl_b = (const float*)d_in[19];
  const float* v_nl_w = (const float*)d_in[20];
  const float* v_nl_b = (const float*)d_in[21];
  const float* ln1_g = (const float*)d_in[22];
  const float* ln1_b = (const float*)d_in[23];
  const float* fc1_w = (const float*)d_in[24];
  const float* fc1_b = (const float*)d_in[25];
  const float* ln2_g = (const float*)d_in[26];
  const float* ln2_b = (const float*)d_in[27];
  const float* fc2_w = (const float*)d_in[28];
  const float* fc2_b = (const float*)d_in[29];
  const float* ln0_g = (const float*)d_in[30];
  const float* ln0_b = (const float*)d_in[31];
  const float* gate_w = (const float*)d_in[32];
  const float* gate_b = (const float*)d_in[33];
  const float* ln3_g = (const float*)d_in[34];
  const float* ln3_b = (const float*)d_in[35];
  const float* fc3_w = (const float*)d_in[36];
  const float* fc3_b = (const float*)d_in[37];
  const float* ln4_g = (const float*)d_in[38];
  const float* ln4_b = (const float*)d_in[39];
  const float* fc4_w = (const float*)d_in[40];
  const float* fc4_b = (const float*)d_in[41];

  const size_t S = (size_t)8192 * 64;
  u16* ub = (u16*)d_ws;
  u16* Qb_nir = ub + 0 * S;
  u16* Kb_nir = ub + 1 * S;
  u16* Vb_nir = ub + 2 * S;
  u16* Qb_libs = ub + 3 * S;
  u16* Kb_libs = ub + 4 * S;
  u16* Vb_libs = ub + 5 * S;
  u16* OpartU = ub + 6 * S;  // 16 slabs bf16 (2 dirs x 8 splits)
  float* fp = (float*)(ub + 22 * S);
  float* f_nir = fp + 0 * S;
  float* f_libs = fp + 1 * S;
  float* lpart = fp + 2 * S;  // 16 x 8192

  extract_fused_kernel<<<512, 256, 0, stream>>>(
      nir_data, libs_data, nir_ln_g, nir_ln_b, nir_w, nir_b, libs_ln_g,
      libs_ln_b, libs_w, libs_b, q_ln_w, q_ln_b, k_ln_w, k_ln_b, v_ln_w,
      v_ln_b, q_nl_w, q_nl_b, k_nl_w, k_nl_b, v_nl_w, v_nl_b, f_nir, f_libs,
      Qb_nir, Kb_nir, Vb_nir, Qb_libs, Kb_libs, Vb_libs);

  // dir0: Q_libs x K/V_nir ; dir1: Q_nir x K/V_libs
  attn_mfma_kernel<<<512, 256, 0, stream>>>(Qb_libs, Kb_nir, Vb_nir, Qb_nir,
                                            Kb_libs, Vb_libs, OpartU, lpart);

  post_kernel<<<1024, 256, 0, stream>>>(
      OpartU, lpart, f_nir, f_libs, ln1_g, ln1_b, fc1_w, fc1_b, ln2_g, ln2_b,
      fc2_w, fc2_b, ln0_g, ln0_b, gate_w, gate_b, ln3_g, ln3_b, fc3_w, fc3_b,
      ln4_g, ln4_b, fc4_w, fc4_b, (float*)d_out);
}